// Round 14
// baseline (7337.972 us; speedup 1.0000x reference)
//
#include <hip/hip_runtime.h>
#include <math.h>

typedef _Float16 f16_t;
typedef _Float16 half8 __attribute__((ext_vector_type(8)));
typedef float f32x4 __attribute__((ext_vector_type(4)));

// small-proj first: Y_k = W_k^T (.) X (K=128); then big GEMM out = Y0 + [Y1|Y2] @ [G;T2] (K=1600).
// biggate fuses CAND small-proj (rh in regs); bigcand0 fuses L1 gate small-proj (h0new in regs);
// bigcand1 fuses attention partial-q (h1new in regs).

struct Params {
  const float *x_seq, *t_x, *t_y, *G;
  const float *Wraw[8], *bia[8];  // idx = dec*4 + layer*2 + cand
  const float *mW1, *mb1, *mW2, *mb2, *mem, *Wa, *fc, *projW, *projb;
  float* dout;
  float *h0, *h1, *txe, *tye, *hidb, *partial, *Wat;
  f16_t *T2h, *Bpk, *Y0g, *Ybg, *Y0c, *Ybc, *Uh;
  f16_t* wsp[8];  // [3][NC][128] folded, transposed, f16
};

__device__ __forceinline__ float sigm(float x) { return 1.0f / (1.0f + expf(-x)); }

__device__ __forceinline__ int xcd_swz(int orig, int nwg) {
  int q = nwg >> 3, r = nwg & 7, xcd = orig & 7, j = orig >> 3;
  return (xcd < r ? xcd * (q + 1) : r * (q + 1) + (xcd - r) * q) + j;
}

__device__ __forceinline__ void gload16(const void* g, void* l) {
  __builtin_amdgcn_global_load_lds((const __attribute__((address_space(1))) void*)g,
                                   (__attribute__((address_space(3))) void*)l, 16, 0, 0);
}

// ================= prologue =================

__global__ void __launch_bounds__(256) k_pre0(Params p) {
  int nt = gridDim.x * blockDim.x, id = blockIdx.x * blockDim.x + threadIdx.x;
  float4 z = {0.f, 0.f, 0.f, 0.f};
  for (int i = id; i < 64 * 64 * 200; i += nt) { ((float4*)p.h0)[i] = z; ((float4*)p.h1)[i] = z; }
  for (int w = 0; w < 8; ++w) {
    int layer = (w >> 1) & 1, cand = w & 1;
    int P = layer ? 128 : 68, NC = cand ? 64 : 128;
    const float* W = p.Wraw[w];
    f16_t* dst = p.wsp[w];
    int tot = 3 * NC * 128;
    for (int idx = id; idx < tot; idx += nt) {
      int s = idx / (NC * 128), rem = idx - s * (NC * 128);
      int c = rem >> 7, pp = rem & 127;
      float v = 0.f;
      if (pp < P) {
        if (s == 0)
          v = W[(size_t)pp * NC + c] + 0.05f * (W[(size_t)(P + pp) * NC + c] + W[(size_t)(2 * P + pp) * NC + c]);
        else
          v = 0.95f * W[(size_t)(s * P + pp) * NC + c];
      }
      dst[idx] = (f16_t)v;
    }
  }
  for (int idx = id; idx < 15360; idx += nt) {
    int half = idx / 7680, rem = idx - half * 7680;
    int r = rem / 10, j = rem - r * 10;
    const float* tin = half ? p.t_y : p.t_x;
    float a = p.mb1[j];
    for (int k = 0; k < 60; ++k) a += tin[(size_t)r * 60 + k] * p.mW1[k * 10 + j];
    p.hidb[idx] = a;
  }
  for (int idx = id; idx < 409600; idx += nt) {
    int c = idx / 6400, r2 = idx - c * 6400;
    int n = r2 >> 3, d = r2 & 7;
    p.Wat[idx] = p.Wa[((size_t)n * 64 + c) * 8 + d];
  }
}

// T2h = 2*G@G - I (f16), plus mlp_out
__global__ void __launch_bounds__(256) k_pre1(Params p) {
  __shared__ float As[16 * 68];
  __shared__ float Bs[16 * 68];
  int tid = threadIdx.x, tx = tid & 15, ty = tid >> 4;
  const float* A = p.G;
  for (int tile = blockIdx.x; tile < 169; tile += gridDim.x) {
    int bx = tile % 13, by = tile / 13;
    int rowBase = by * 64, colBase = bx * 64;
    float acc[4][4] = {};
    for (int k0 = 0; k0 < 800; k0 += 16) {
      __syncthreads();
      for (int e = tid; e < 1024; e += 256) {
        int r = e >> 4, c = e & 15;
        int gr = rowBase + r;
        As[c * 68 + r] = (gr < 800) ? A[gr * 800 + k0 + c] : 0.f;
      }
      for (int e = tid; e < 1024; e += 256) {
        int r = e >> 6, c = e & 63;
        int gc = colBase + c;
        Bs[r * 68 + c] = (gc < 800) ? A[(k0 + r) * 800 + gc] : 0.f;
      }
      __syncthreads();
#pragma unroll
      for (int kk = 0; kk < 16; ++kk) {
        float4 a4 = *(const float4*)&As[kk * 68 + ty * 4];
        float4 b4 = *(const float4*)&Bs[kk * 68 + tx * 4];
        float av[4] = {a4.x, a4.y, a4.z, a4.w};
        float bv[4] = {b4.x, b4.y, b4.z, b4.w};
#pragma unroll
        for (int i = 0; i < 4; ++i)
#pragma unroll
          for (int j = 0; j < 4; ++j) acc[i][j] += av[i] * bv[j];
      }
    }
#pragma unroll
    for (int i = 0; i < 4; ++i) {
      int m = rowBase + ty * 4 + i;
      if (m >= 800) continue;
#pragma unroll
      for (int j = 0; j < 4; ++j) {
        int n = colBase + tx * 4 + j;
        if (n < 800) p.T2h[(size_t)m * 800 + n] = (f16_t)(2.f * acc[i][j] - (m == n ? 1.f : 0.f));
      }
    }
  }
  int nt = gridDim.x * blockDim.x, id = blockIdx.x * blockDim.x + threadIdx.x;
  for (int idx = id; idx < 2 * 768 * 1600; idx += nt) {
    int half = idx / (768 * 1600), rem = idx - half * (768 * 1600);
    int r = rem / 1600, o = rem - r * 1600;
    const float* hid = p.hidb + half * 7680;
    float* emb = half ? p.tye : p.txe;
    float a = p.mb2[o];
#pragma unroll
    for (int k = 0; k < 10; ++k) a += hid[r * 10 + k] * p.mW2[k * 1600 + o];
    emb[rem] = a;
  }
}

// Bpk[nT][ks][kg][col][8]: value Bstk[k'][n], k' = ks*32+kg*8+e, n = nT*128+col; zero-pad n>=800
__global__ void __launch_bounds__(256) k_pre2(Params p) {
  int nt = gridDim.x * blockDim.x, id = blockIdx.x * blockDim.x + threadIdx.x;
  for (int idx = id; idx < 7 * 50 * 4096; idx += nt) {
    int nT = idx / 204800, rem = idx - nT * 204800;
    int ks = rem >> 12, i = rem & 4095;
    int kg = i >> 10, col = (i >> 3) & 127, e = i & 7;
    int k = ks * 32 + kg * 8 + e;
    int n = nT * 128 + col;
    f16_t v = (f16_t)0.f;
    if (n < 800) v = (k < 800) ? (f16_t)p.G[(size_t)k * 800 + n] : p.T2h[(size_t)(k - 800) * 800 + n];
    p.Bpk[idx] = v;
  }
}

// ================= L0 gate small proj =================
__global__ void __launch_bounds__(256, 3) g_small0(Params p, int widx, int dec, int t) {
  __shared__ f16_t XS[128 * 136];
  unsigned* XS32 = (unsigned*)XS;
  int tid = threadIdx.x, lane = tid & 63, wid = tid >> 6;
  int lrow = lane & 15, lgrp = lane >> 4;
  int wm = wid >> 1, wn = wid & 1;
  int swz = xcd_swz(blockIdx.x, gridDim.x);
  int b = swz / 7, nBase = (swz % 7) * 128;
  const f16_t* __restrict__ wb = p.wsp[widx];
  const float* emb = dec ? p.tye : p.txe;

  {
    int rp = tid >> 3, n0 = (tid & 7) * 16;
    int ng = nBase + n0;
    bool nval = ng < 800;
    for (int pass = 0; pass < 2; ++pass) {
      float v[2][16];
#pragma unroll
      for (int par = 0; par < 2; ++par) {
        int cp = pass * 64 + 2 * rp + par;
        float* vv = v[par];
        if (!nval || cp >= 68) {
#pragma unroll
          for (int i = 0; i < 16; ++i) vv[i] = 0.f;
        } else if (cp >= 4) {
          const float* src = p.h0 + ((size_t)(b * 64 + cp - 4)) * 800 + ng;
#pragma unroll
          for (int q = 0; q < 4; ++q) {
            float4 f = *(const float4*)(src + q * 4);
            vv[q * 4 + 0] = f.x; vv[q * 4 + 1] = f.y; vv[q * 4 + 2] = f.z; vv[q * 4 + 3] = f.w;
          }
        } else if (cp >= 2) {
#pragma unroll
          for (int i = 0; i < 16; ++i)
            vv[i] = emb[(size_t)(b * 12 + t) * 1600 + (ng + i) * 2 + (cp - 2)];
        } else {
          if (dec) {
            if (t == 0) {
#pragma unroll
              for (int i = 0; i < 16; ++i) vv[i] = 0.f;
            } else {
#pragma unroll
              for (int i = 0; i < 16; ++i)
                vv[i] = p.dout[((size_t)(b * 12 + t - 1) * 800 + ng + i) * 2 + cp];
            }
          } else {
#pragma unroll
            for (int i = 0; i < 16; ++i)
              vv[i] = p.x_seq[((size_t)(b * 12 + t) * 800 + ng + i) * 2 + cp];
          }
        }
      }
#pragma unroll
      for (int i = 0; i < 16; ++i) {
        union { f16_t h[2]; unsigned u; } pk;
        pk.h[0] = (f16_t)v[0][i];
        pk.h[1] = (f16_t)v[1][i];
        XS32[(n0 + i) * 68 + pass * 32 + rp] = pk.u;
      }
    }
  }
  __syncthreads();

  for (int s = 0; s < 3; ++s) {
    f32x4 acc[4][4];
#pragma unroll
    for (int i = 0; i < 4; ++i)
#pragma unroll
      for (int j = 0; j < 4; ++j) acc[i][j] = (f32x4){0.f, 0.f, 0.f, 0.f};
#pragma unroll
    for (int ks = 0; ks < 4; ++ks) {
      half8 fa[4], fx[4];
#pragma unroll
      for (int mf = 0; mf < 4; ++mf)
        fa[mf] = *(const half8*)(wb + ((size_t)(s * 128 + wm * 64 + mf * 16 + lrow) << 7) + ks * 32 + lgrp * 8);
#pragma unroll
      for (int nt = 0; nt < 4; ++nt)
        fx[nt] = *(const half8*)(XS + (wn * 64 + nt * 16 + lrow) * 136 + ks * 32 + lgrp * 8);
#pragma unroll
      for (int mf = 0; mf < 4; ++mf)
#pragma unroll
        for (int nt = 0; nt < 4; ++nt)
          acc[mf][nt] = __builtin_amdgcn_mfma_f32_16x16x32_f16(fa[mf], fx[nt], acc[mf][nt], 0, 0, 0);
    }
#pragma unroll
    for (int mf = 0; mf < 4; ++mf)
#pragma unroll
      for (int nt = 0; nt < 4; ++nt) {
        int n = nBase + wn * 64 + nt * 16 + lrow;
        if (n >= 800) continue;
#pragma unroll
        for (int j = 0; j < 4; ++j) {
          int c = wm * 64 + mf * 16 + lgrp * 4 + j;
          size_t r = (size_t)(b * 128 + c);
          f16_t val = (f16_t)acc[mf][nt][j];
          if (s == 0) {
            p.Y0g[r * 800 + n] = val;
          } else {
            int kp = (s - 1) * 800 + n;
            p.Ybg[((size_t)(kp >> 3) * 8192 + r) * 8 + (kp & 7)] = val;
          }
        }
      }
  }
}

// ================= gate big GEMM (M=8192) + fused CAND small-proj in rh-half blocks =========
template <int LAYER>
__global__ void __launch_bounds__(256, 4) g_biggate(Params p, int w0, int dec, int t, float* hcur) {
  constexpr int Pin = LAYER ? 64 : 4;
  __shared__ __align__(16) f16_t SH[18432];
  f16_t* AS = SH;
  f16_t* BS = SH + 6144;
  int tid = threadIdx.x, lane = tid & 63, w = tid >> 6;
  int lrow = lane & 15, lgrp = lane >> 4;
  int wm = w >> 1, wn = w & 1;
  int swz = xcd_swz(blockIdx.x, gridDim.x);
  int rt = swz / 7;
  int rBase = rt * 64;
  int nTile = swz % 7;
  int b = rt >> 1;
  int rhblk = rt & 1;
  const f16_t* __restrict__ Abase = p.Ybg;
  const f16_t* __restrict__ Bbase = p.Bpk + (size_t)nTile * 204800;
  const float* bias = p.bia[w0];

  auto stage = [&](int buf, int ks) {
    gload16(Abase + ((size_t)(ks * 4 + w) * 8192 + rBase + lane) * 8, AS + buf * 2048 + w * 512);
    gload16(Bbase + (size_t)ks * 4096 + (size_t)(w * 2 + 0) * 512 + lane * 8, BS + buf * 4096 + (w * 2 + 0) * 512);
    gload16(Bbase + (size_t)ks * 4096 + (size_t)(w * 2 + 1) * 512 + lane * 8, BS + buf * 4096 + (w * 2 + 1) * 512);
  };

  f32x4 acc[2][4];
#pragma unroll
  for (int i = 0; i < 2; ++i)
#pragma unroll
    for (int j = 0; j < 4; ++j) acc[i][j] = (f32x4){0.f, 0.f, 0.f, 0.f};

  stage(0, 0);
  stage(1, 1);
  for (int ks = 0; ks < 50; ++ks) {
    if (ks == 49) {
      asm volatile("s_waitcnt vmcnt(0)" ::: "memory");
    } else {
      asm volatile("s_waitcnt vmcnt(3)" ::: "memory");
    }
    __builtin_amdgcn_s_barrier();
    __builtin_amdgcn_sched_barrier(0);
    int cur = ks % 3;
    half8 fa[2], fb[4];
#pragma unroll
    for (int mt = 0; mt < 2; ++mt)
      fa[mt] = *(const half8*)(AS + cur * 2048 + lgrp * 512 + (wm * 32 + mt * 16 + lrow) * 8);
#pragma unroll
    for (int nt = 0; nt < 4; ++nt)
      fb[nt] = *(const half8*)(BS + cur * 4096 + lgrp * 1024 + (wn * 64 + nt * 16 + lrow) * 8);
    if (ks + 2 < 50) stage((ks + 2) % 3, ks + 2);
#pragma unroll
    for (int mt = 0; mt < 2; ++mt)
#pragma unroll
      for (int nt = 0; nt < 4; ++nt)
        acc[mt][nt] = __builtin_amdgcn_mfma_f32_16x16x32_f16(fa[mt], fb[nt], acc[mt][nt], 0, 0, 0);
  }

  if (!rhblk) {
#pragma unroll
    for (int mt = 0; mt < 2; ++mt)
#pragma unroll
      for (int nt = 0; nt < 4; ++nt) {
        int n = nTile * 128 + wn * 64 + nt * 16 + lrow;
        if (n >= 800) continue;
#pragma unroll
        for (int j = 0; j < 4; ++j) {
          int c = wm * 32 + mt * 16 + lgrp * 4 + j;
          int r = rBase + c;
          float v = acc[mt][nt][j] + (float)p.Y0g[(size_t)r * 800 + n] + bias[c];
          p.Uh[(size_t)(b * 64 + c) * 800 + n] = (f16_t)sigm(v);
        }
      }
    return;
  }

  f16_t rhv[2][4][4];
#pragma unroll
  for (int mt = 0; mt < 2; ++mt)
#pragma unroll
    for (int nt = 0; nt < 4; ++nt) {
      int n = nTile * 128 + wn * 64 + nt * 16 + lrow;
#pragma unroll
      for (int j = 0; j < 4; ++j) {
        int jj = wm * 32 + mt * 16 + lgrp * 4 + j;
        if (n < 800) {
          int r = rBase + jj;
          float v = acc[mt][nt][j] + (float)p.Y0g[(size_t)r * 800 + n] + bias[64 + jj];
          float hv = hcur[(size_t)(b * 64 + jj) * 800 + n];
          rhv[mt][nt][j] = (f16_t)(sigm(v) * hv);
        } else {
          rhv[mt][nt][j] = (f16_t)0.f;
        }
      }
    }

  __syncthreads();
  f16_t* Xc = SH;

#pragma unroll
  for (int mt = 0; mt < 2; ++mt)
#pragma unroll
    for (int nt = 0; nt < 4; ++nt) {
      int col = wn * 64 + nt * 16 + lrow;
#pragma unroll
      for (int j = 0; j < 4; ++j) {
        int jj = wm * 32 + mt * 16 + lgrp * 4 + j;
        Xc[col * 136 + Pin + jj] = rhv[mt][nt][j];
      }
    }
  if (LAYER == 1) {
    int ct = tid >> 2, nq = tid & 3;
    const float* src = p.h0 + (size_t)(b * 64 + ct) * 800;
#pragma unroll 8
    for (int i = 0; i < 32; ++i) {
      int nl = nq * 32 + i;
      int n = nTile * 128 + nl;
      float v = (n < 800) ? src[n] : 0.f;
      Xc[nl * 136 + ct] = (f16_t)v;
    }
  } else {
    if (tid < 128) {
      int col = tid;
      int n = nTile * 128 + col;
      float v0 = 0.f, v1 = 0.f, v2 = 0.f, v3 = 0.f;
      if (n < 800) {
        if (dec) {
          if (t > 0) {
            v0 = p.dout[((size_t)(b * 12 + t - 1) * 800 + n) * 2 + 0];
            v1 = p.dout[((size_t)(b * 12 + t - 1) * 800 + n) * 2 + 1];
          }
        } else {
          v0 = p.x_seq[((size_t)(b * 12 + t) * 800 + n) * 2 + 0];
          v1 = p.x_seq[((size_t)(b * 12 + t) * 800 + n) * 2 + 1];
        }
        const float* emb = dec ? p.tye : p.txe;
        v2 = emb[(size_t)(b * 12 + t) * 1600 + n * 2 + 0];
        v3 = emb[(size_t)(b * 12 + t) * 1600 + n * 2 + 1];
      }
      Xc[col * 136 + 0] = (f16_t)v0;
      Xc[col * 136 + 1] = (f16_t)v1;
      Xc[col * 136 + 2] = (f16_t)v2;
      Xc[col * 136 + 3] = (f16_t)v3;
      unsigned* z32 = (unsigned*)(Xc + col * 136 + 68);
#pragma unroll
      for (int q = 0; q < 30; ++q) z32[q] = 0u;
    }
  }
  __syncthreads();

  const f16_t* __restrict__ wc = p.wsp[w0 + 1];
  int cwn = w;
  for (int s = 0; s < 3; ++s) {
    f32x4 ac[4][2];
#pragma unroll
    for (int i = 0; i < 4; ++i)
#pragma unroll
      for (int j = 0; j < 2; ++j) ac[i][j] = (f32x4){0.f, 0.f, 0.f, 0.f};
#pragma unroll
    for (int ks = 0; ks < 4; ++ks) {
      half8 fa[4], fx[2];
#pragma unroll
      for (int mf = 0; mf < 4; ++mf)
        fa[mf] = *(const half8*)(wc + ((size_t)(s * 64 + mf * 16 + lrow) << 7) + ks * 32 + lgrp * 8);
#pragma unroll
      for (int nt = 0; nt < 2; ++nt)
        fx[nt] = *(const half8*)(Xc + (cwn * 32 + nt * 16 + lrow) * 136 + ks * 32 + lgrp * 8);
#pragma unroll
      for (int mf = 0; mf < 4; ++mf)
#pragma unroll
        for (int nt = 0; nt < 2; ++nt)
          ac[mf][nt] = __builtin_amdgcn_mfma_f32_16x16x32_f16(fa[mf], fx[nt], ac[mf][nt], 0, 0, 0);
    }
#pragma unroll
    for (int mf = 0; mf < 4; ++mf)
#pragma unroll
      for (int nt = 0; nt < 2; ++nt) {
        int n = nTile * 128 + cwn * 32 + nt * 16 + lrow;
        if (n >= 800) continue;
#pragma unroll
        for (int j = 0; j < 4; ++j) {
          int c = mf * 16 + lgrp * 4 + j;
          size_t r = (size_t)(b * 64 + c);
          f16_t val = (f16_t)ac[mf][nt][j];
          if (s == 0) {
            p.Y0c[r * 800 + n] = val;
          } else {
            int kp = (s - 1) * 800 + n;
            p.Ybc[((size_t)(kp >> 3) * 4096 + r) * 8 + (kp & 7)] = val;
          }
        }
      }
  }
}

// ======= L0 cand big GEMM (M=4096) + h0 update + fused L1 GATE small-proj =======
__global__ void __launch_bounds__(256, 4) g_bigcand0(Params p, int w0) {
  __shared__ __align__(16) f16_t SH[18432];
  f16_t* AS = SH;
  f16_t* BS = SH + 6144;
  int tid = threadIdx.x, lane = tid & 63, w = tid >> 6;
  int lrow = lane & 15, lgrp = lane >> 4;
  int wm = w >> 1, wn = w & 1;
  int swz = xcd_swz(blockIdx.x, gridDim.x);
  int b = swz / 7;
  int rBase = b * 64;
  int nTile = swz % 7;
  const f16_t* __restrict__ Abase = p.Ybc;
  const f16_t* __restrict__ Bbase = p.Bpk + (size_t)nTile * 204800;
  const float* bias = p.bia[w0 + 1];

  auto stage = [&](int buf, int ks) {
    gload16(Abase + ((size_t)(ks * 4 + w) * 4096 + rBase + lane) * 8, AS + buf * 2048 + w * 512);
    gload16(Bbase + (size_t)ks * 4096 + (size_t)(w * 2 + 0) * 512 + lane * 8, BS + buf * 4096 + (w * 2 + 0) * 512);
    gload16(Bbase + (size_t)ks * 4096 + (size_t)(w * 2 + 1) * 512 + lane * 8, BS + buf * 4096 + (w * 2 + 1) * 512);
  };

  f32x4 acc[2][4];
#pragma unroll
  for (int i = 0; i < 2; ++i)
#pragma unroll
    for (int j = 0; j < 4; ++j) acc[i][j] = (f32x4){0.f, 0.f, 0.f, 0.f};

  stage(0, 0);
  stage(1, 1);
  for (int ks = 0; ks < 50; ++ks) {
    if (ks == 49) {
      asm volatile("s_waitcnt vmcnt(0)" ::: "memory");
    } else {
      asm volatile("s_waitcnt vmcnt(3)" ::: "memory");
    }
    __builtin_amdgcn_s_barrier();
    __builtin_amdgcn_sched_barrier(0);
    int cur = ks % 3;
    half8 fa[2], fb[4];
#pragma unroll
    for (int mt = 0; mt < 2; ++mt)
      fa[mt] = *(const half8*)(AS + cur * 2048 + lgrp * 512 + (wm * 32 + mt * 16 + lrow) * 8);
#pragma unroll
    for (int nt = 0; nt < 4; ++nt)
      fb[nt] = *(const half8*)(BS + cur * 4096 + lgrp * 1024 + (wn * 64 + nt * 16 + lrow) * 8);
    if (ks + 2 < 50) stage((ks + 2) % 3, ks + 2);
#pragma unroll
    for (int mt = 0; mt < 2; ++mt)
#pragma unroll
      for (int nt = 0; nt < 4; ++nt)
        acc[mt][nt] = __builtin_amdgcn_mfma_f32_16x16x32_f16(fa[mt], fb[nt], acc[mt][nt], 0, 0, 0);
  }

  // h0 update; keep h0new (f16) in regs
  f16_t hnew[2][4][4];
#pragma unroll
  for (int mt = 0; mt < 2; ++mt)
#pragma unroll
    for (int nt = 0; nt < 4; ++nt) {
      int n = nTile * 128 + wn * 64 + nt * 16 + lrow;
#pragma unroll
      for (int j = 0; j < 4; ++j) {
        int c = wm * 32 + mt * 16 + lgrp * 4 + j;
        int r = rBase + c;
        if (n < 800) {
          float v = acc[mt][nt][j] + (float)p.Y0c[(size_t)r * 800 + n] + bias[c];
          float u = (float)p.Uh[(size_t)(b * 64 + c) * 800 + n];
          float hv = p.h0[(size_t)(b * 64 + c) * 800 + n];
          float hn = (1.f - u) * hv + u * tanhf(v);
          p.h0[(size_t)(b * 64 + c) * 800 + n] = hn;
          hnew[mt][nt][j] = (f16_t)hn;
        } else {
          hnew[mt][nt][j] = (f16_t)0.f;
        }
      }
    }

  __syncthreads();
  f16_t* Xs = SH;  // [n 128][c' 128] pitch 136: c' = [h0new 64 | h1 64]

#pragma unroll
  for (int mt = 0; mt < 2; ++mt)
#pragma unroll
    for (int nt = 0; nt < 4; ++nt) {
      int col = wn * 64 + nt * 16 + lrow;
#pragma unroll
      for (int j = 0; j < 4; ++j) {
        int c = wm * 32 + mt * 16 + lgrp * 4 + j;
        Xs[col * 136 + c] = hnew[mt][nt][j];
      }
    }
  {
    int ct = tid >> 2, nq = tid & 3;
    const float* src = p.h1 + (size_t)(b * 64 + ct) * 800;
#pragma unroll 8
    for (int i = 0; i < 32; ++i) {
      int nl = nq * 32 + i;
      int n = nTile * 128 + nl;
      float v = (n < 800) ? src[n] : 0.f;
      Xs[nl * 136 + 64 + ct] = (f16_t)v;
    }
  }
  __syncthreads();

  // L1 GATE small GEMM: 3 slices, M=128, N=128; weights wsp[w0+2]
  const f16_t* __restrict__ wb = p.wsp[w0 + 2];
  for (int s = 0; s < 3; ++s) {
    f32x4 ac[4][4];
#pragma unroll
    for (int i = 0; i < 4; ++i)
#pragma unroll
      for (int j = 0; j < 4; ++j) ac[i][j] = (f32x4){0.f, 0.f, 0.f, 0.f};
#pragma unroll
    for (int ks = 0; ks < 4; ++ks) {
      half8 fa[4], fx[4];
#pragma unroll
      for (int mf = 0; mf < 4; ++mf)
        fa[mf] = *(const half8*)(wb + ((size_t)(s * 128 + wm * 64 + mf * 16 + lrow) << 7) + ks * 32 + lgrp * 8);
#pragma unroll
      for (int nt = 0; nt < 4; ++nt)
        fx[nt] = *(const half8*)(Xs + (wn * 64 + nt * 16 + lrow) * 136 + ks * 32 + lgrp * 8);
#pragma unroll
      for (int mf = 0; mf < 4; ++mf)
#pragma unroll
        for (int nt = 0; nt < 4; ++nt)
          ac[mf][nt] = __builtin_amdgcn_mfma_f32_16x16x32_f16(fa[mf], fx[nt], ac[mf][nt], 0, 0, 0);
    }
#pragma unroll
    for (int mf = 0; mf < 4; ++mf)
#pragma unroll
      for (int nt = 0; nt < 4; ++nt) {
        int n = nTile * 128 + wn * 64 + nt * 16 + lrow;
        if (n >= 800) continue;
#pragma unroll
        for (int j = 0; j < 4; ++j) {
          int c = wm * 64 + mf * 16 + lgrp * 4 + j;
          size_t r = (size_t)(b * 128 + c);
          f16_t val = (f16_t)ac[mf][nt][j];
          if (s == 0) {
            p.Y0g[r * 800 + n] = val;
          } else {
            int kp = (s - 1) * 800 + n;
            p.Ybg[((size_t)(kp >> 3) * 8192 + r) * 8 + (kp & 7)] = val;
          }
        }
      }
  }
}

// ======= L1 cand big GEMM (M=4096) + h1 update + fused attention partial-q =======
__global__ void __launch_bounds__(256, 4) g_bigcand1(Params p, int w0, int doatt) {
  __shared__ __align__(16) f16_t SH[18432];
  f16_t* AS = SH;
  f16_t* BS = SH + 6144;
  int tid = threadIdx.x, lane = tid & 63, w = tid >> 6;
  int lrow = lane & 15, lgrp = lane >> 4;
  int wm = w >> 1, wn = w & 1;
  int swz = xcd_swz(blockIdx.x, gridDim.x);
  int b = swz / 7;
  int rBase = b * 64;
  int nTile = swz % 7;
  const f16_t* __restrict__ Abase = p.Ybc;
  const f16_t* __restrict__ Bbase = p.Bpk + (size_t)nTile * 204800;
  const float* bias = p.bia[w0 + 3];

  auto stage = [&](int buf, int ks) {
    gload16(Abase + ((size_t)(ks * 4 + w) * 4096 + rBase + lane) * 8, AS + buf * 2048 + w * 512);
    gload16(Bbase + (size_t)ks * 4096 + (size_t)(w * 2 + 0) * 512 + lane * 8, BS + buf * 4096 + (w * 2 + 0) * 512);
    gload16(Bbase + (size_t)ks * 4096 + (size_t)(w * 2 + 1) * 512 + lane * 8, BS + buf * 4096 + (w * 2 + 1) * 512);
  };

  f32x4 acc[2][4];
#pragma unroll
  for (int i = 0; i < 2; ++i)
#pragma unroll
    for (int j = 0; j < 4; ++j) acc[i][j] = (f32x4){0.f, 0.f, 0.f, 0.f};

  stage(0, 0);
  stage(1, 1);
  for (int ks = 0; ks < 50; ++ks) {
    if (ks == 49) {
      asm volatile("s_waitcnt vmcnt(0)" ::: "memory");
    } else {
      asm volatile("s_waitcnt vmcnt(3)" ::: "memory");
    }
    __builtin_amdgcn_s_barrier();
    __builtin_amdgcn_sched_barrier(0);
    int cur = ks % 3;
    half8 fa[2], fb[4];
#pragma unroll
    for (int mt = 0; mt < 2; ++mt)
      fa[mt] = *(const half8*)(AS + cur * 2048 + lgrp * 512 + (wm * 32 + mt * 16 + lrow) * 8);
#pragma unroll
    for (int nt = 0; nt < 4; ++nt)
      fb[nt] = *(const half8*)(BS + cur * 4096 + lgrp * 1024 + (wn * 64 + nt * 16 + lrow) * 8);
    if (ks + 2 < 50) stage((ks + 2) % 3, ks + 2);
#pragma unroll
    for (int mt = 0; mt < 2; ++mt)
#pragma unroll
      for (int nt = 0; nt < 4; ++nt)
        acc[mt][nt] = __builtin_amdgcn_mfma_f32_16x16x32_f16(fa[mt], fb[nt], acc[mt][nt], 0, 0, 0);
  }

  float qd[8] = {};
#pragma unroll
  for (int mt = 0; mt < 2; ++mt)
#pragma unroll
    for (int nt = 0; nt < 4; ++nt) {
      int n = nTile * 128 + wn * 64 + nt * 16 + lrow;
#pragma unroll
      for (int j = 0; j < 4; ++j) {
        int c = wm * 32 + mt * 16 + lgrp * 4 + j;
        if (n < 800) {
          float v = acc[mt][nt][j] + (float)p.Y0c[(size_t)(rBase + c) * 800 + n] + bias[c];
          float u = (float)p.Uh[(size_t)(b * 64 + c) * 800 + n];
          float hv = p.h1[(size_t)(b * 64 + c) * 800 + n];
          float hn = (1.f - u) * hv + u * tanhf(v);
          p.h1[(size_t)(b * 64 + c) * 800 + n] = hn;
          if (doatt) {
            const float* wr = p.Wat + ((size_t)c * 800 + n) * 8;
#pragma unroll
            for (int d = 0; d < 8; ++d) qd[d] += hn * wr[d];
          }
        }
      }
    }

  if (doatt) {
#pragma unroll
    for (int s = 1; s < 64; s <<= 1) {
#pragma unroll
      for (int d = 0; d < 8; ++d) qd[d] += __shfl_xor(qd[d], s);
    }
    __syncthreads();
    float* red = (float*)SH;
    if (lane == 0) {
#pragma unroll
      for (int d = 0; d < 8; ++d) red[w * 8 + d] = qd[d];
    }
    __syncthreads();
    if (tid == 0) {
#pragma unroll
      for (int d = 0; d < 8; ++d)
        p.partial[((size_t)b * 7 + nTile) * 8 + d] = red[d] + red[8 + d] + red[16 + d] + red[24 + d];
    }
  }
}

// ================= attention epilogue: softmax + output projection =================

__global__ void __launch_bounds__(256) k_att2(Params p, int t) {
  int b = blockIdx.x >> 2, q4 = blockIdx.x & 3;
  int tid = threadIdx.x;
  float qv[8] = {};
  for (int cx = 0; cx < 7; ++cx)
#pragma unroll
    for (int j = 0; j < 8; ++j) qv[j] += p.partial[((size_t)b * 7 + cx) * 8 + j];
  float sco[4], mx = -1e30f;
#pragma unroll
  for (int m = 0; m < 4; ++m) {
    float s = 0.f;
#pragma unroll
    for (int d = 0; d < 8; ++d) s += qv[d] * p.mem[m * 8 + d];
    sco[m] = s;
    mx = fmaxf(mx, s);
  }
  float se = 0.f;
#pragma unroll
  for (int m = 0; m < 4; ++m) { sco[m] = expf(sco[m] - mx); se += sco[m]; }
  float attv[8];
#pragma unroll
  for (int d = 0; d < 8; ++d) {
    float av = 0.f;
#pragma unroll
    for (int m = 0; m < 4; ++m) av += (sco[m] / se) * p.mem[m * 8 + d];
    attv[d] = av;
  }
  if (tid >= 200) return;
  int n = q4 * 200 + tid;
  float attm[8];
#pragma unroll
  for (int d = 0; d < 8; ++d) {
    float s = 0.f;
#pragma unroll
    for (int m = 0; m < 8; ++m) s += attv[m] * p.fc[(size_t)m * 6400 + n * 8 + d];
    attm[d] = s;
  }
  float o0 = p.projb[0], o1 = p.projb[1];
  const float* hb = p.h1 + (size_t)b * 51200 + n;
#pragma unroll 16
  for (int j = 0; j < 64; ++j) {
    float hv = hb[(size_t)j * 800];
    o0 += hv * p.projW[j * 2 + 0];
    o1 += hv * p.projW[j * 2 + 1];
  }
#pragma unroll
  for (int d = 0; d < 8; ++d) {
    o0 += attm[d] * p.projW[(64 + d) * 2 + 0];
    o1 += attm[d] * p.projW[(64 + d) * 2 + 1];
  }
  size_t base = ((size_t)(b * 12 + t) * 800 + n) * 2;
  p.dout[base + 0] = fmaxf(o0, 0.f);
  p.dout[base + 1] = fmaxf(o1, 0.f);
}

// ================= host =================

extern "C" void kernel_launch(void* const* d_in, const int* in_sizes, int n_in,
                              void* d_out, int out_size, void* d_ws, size_t ws_size,
                              hipStream_t stream) {
  Params P;
  P.x_seq = (const float*)d_in[0];
  P.t_x = (const float*)d_in[1];
  P.t_y = (const float*)d_in[2];
  P.G = (const float*)d_in[3];
  P.Wraw[0] = (const float*)d_in[4];  P.bia[0] = (const float*)d_in[5];
  P.Wraw[1] = (const float*)d_in[6];  P.bia[1] = (const float*)d_in[7];
  P.Wraw[2] = (const float*)d_in[8];  P.bia[2] = (const float*)d_in[9];
  P.Wraw[3] = (const float*)d_in[10]; P.bia[3] = (const float*)d_in[11];
  P.Wraw[4] = (const float*)d_in[12]; P.bia[4] = (const float*)d_in[13];
  P.Wraw[5] = (const float*)d_in[14]; P.bia[5] = (const float*)d_in[15];
  P.Wraw[6] = (const float*)d_in[16]; P.bia[6] = (const float*)d_in[17];
  P.Wraw[7] = (const float*)d_in[18]; P.bia[7] = (const float*)d_in[19];
  P.mW1 = (const float*)d_in[20];
  P.mb1 = (const float*)d_in[21];
  P.mW2 = (const float*)d_in[22];
  P.mb2 = (const float*)d_in[23];
  P.mem = (const float*)d_in[24];
  P.Wa = (const float*)d_in[25];
  P.fc = (const float*)d_in[26];
  P.projW = (const float*)d_in[27];
  P.projb = (const float*)d_in[28];
  P.dout = (float*)d_out;

  float* ws = (float*)d_ws;
  size_t off = 0;
  auto alloc = [&](size_t nel) { float* q = ws + off; off += (nel + 3) & ~(size_t)3; return q; };
  P.T2h = (f16_t*)alloc(320000);
  P.Bpk = (f16_t*)alloc((size_t)7 * 50 * 4096 / 2);
  P.Y0g = (f16_t*)alloc((size_t)8192 * 800 / 2);
  P.Ybg = (f16_t*)alloc((size_t)1600 * 8192 / 2);
  P.Y0c = (f16_t*)alloc((size_t)4096 * 800 / 2);
  P.Ybc = (f16_t*)alloc((size_t)1600 * 4096 / 2);
  P.Uh = (f16_t*)alloc((size_t)4096 * 800 / 2);
  P.h0 = alloc((size_t)4096 * 800);
  P.h1 = alloc((size_t)4096 * 800);
  P.txe = alloc((size_t)768 * 1600);
  P.tye = alloc((size_t)768 * 1600);
  P.hidb = alloc(15360);
  P.partial = alloc(64 * 7 * 8);
  P.Wat = alloc(409600);
  for (int w = 0; w < 8; ++w) {
    int cand = w & 1;
    int NC = cand ? 64 : 128;
    P.wsp[w] = (f16_t*)alloc((size_t)3 * NC * 128 / 2);
  }

  k_pre0<<<512, 256, 0, stream>>>(P);
  k_pre1<<<512, 256, 0, stream>>>(P);
  k_pre2<<<512, 256, 0, stream>>>(P);

  auto cell = [&](int dec, int t) {
    int w0 = dec * 4;
    g_small0<<<448, 256, 0, stream>>>(P, w0 + 0, dec, t);
    g_biggate<0><<<896, 256, 0, stream>>>(P, w0 + 0, dec, t, P.h0);
    g_bigcand0<<<448, 256, 0, stream>>>(P, w0);
    g_biggate<1><<<896, 256, 0, stream>>>(P, w0 + 2, dec, t, P.h1);
    g_bigcand1<<<448, 256, 0, stream>>>(P, w0, dec);
  };

  for (int t = 0; t < 12; ++t) cell(0, t);
  for (int t = 0; t < 12; ++t) {
    cell(1, t);
    k_att2<<<256, 256, 0, stream>>>(P, t);
  }
}

// Round 15
// 6597.384 us; speedup vs baseline: 1.1123x; 1.1123x over previous
//
#include <hip/hip_runtime.h>
#include <math.h>

typedef _Float16 f16_t;
typedef _Float16 half8 __attribute__((ext_vector_type(8)));
typedef float f32x4 __attribute__((ext_vector_type(4)));

// small-proj first: Y_k = W_k^T (.) X (K=128); then big GEMM out = Y0 + [Y1|Y2] @ [G;T2] (K=1600).
// Gate big-GEMM fuses the CAND small-proj in its rh-half blocks (rh never hits HBM).
// R15 = R13 revert + issue-early prefetch in the big-GEMM k-loop.

struct Params {
  const float *x_seq, *t_x, *t_y, *G;
  const float *Wraw[8], *bia[8];  // idx = dec*4 + layer*2 + cand
  const float *mW1, *mb1, *mW2, *mb2, *mem, *Wa, *fc, *projW, *projb;
  float* dout;
  float *h0, *h1, *txe, *tye, *hidb, *partial, *Wat;
  f16_t *T2h, *Bpk, *Y0g, *Ybg, *Y0c, *Ybc, *Uh;
  f16_t* wsp[8];  // [3][NC][128] folded, transposed, f16
};

__device__ __forceinline__ float sigm(float x) { return 1.0f / (1.0f + expf(-x)); }

__device__ __forceinline__ int xcd_swz(int orig, int nwg) {
  int q = nwg >> 3, r = nwg & 7, xcd = orig & 7, j = orig >> 3;
  return (xcd < r ? xcd * (q + 1) : r * (q + 1) + (xcd - r) * q) + j;
}

__device__ __forceinline__ void gload16(const void* g, void* l) {
  __builtin_amdgcn_global_load_lds((const __attribute__((address_space(1))) void*)g,
                                   (__attribute__((address_space(3))) void*)l, 16, 0, 0);
}

// ================= prologue =================

__global__ void __launch_bounds__(256) k_pre0(Params p) {
  int nt = gridDim.x * blockDim.x, id = blockIdx.x * blockDim.x + threadIdx.x;
  float4 z = {0.f, 0.f, 0.f, 0.f};
  for (int i = id; i < 64 * 64 * 200; i += nt) { ((float4*)p.h0)[i] = z; ((float4*)p.h1)[i] = z; }
  for (int w = 0; w < 8; ++w) {
    int layer = (w >> 1) & 1, cand = w & 1;
    int P = layer ? 128 : 68, NC = cand ? 64 : 128;
    const float* W = p.Wraw[w];
    f16_t* dst = p.wsp[w];
    int tot = 3 * NC * 128;
    for (int idx = id; idx < tot; idx += nt) {
      int s = idx / (NC * 128), rem = idx - s * (NC * 128);
      int c = rem >> 7, pp = rem & 127;
      float v = 0.f;
      if (pp < P) {
        if (s == 0)
          v = W[(size_t)pp * NC + c] + 0.05f * (W[(size_t)(P + pp) * NC + c] + W[(size_t)(2 * P + pp) * NC + c]);
        else
          v = 0.95f * W[(size_t)(s * P + pp) * NC + c];
      }
      dst[idx] = (f16_t)v;
    }
  }
  for (int idx = id; idx < 15360; idx += nt) {
    int half = idx / 7680, rem = idx - half * 7680;
    int r = rem / 10, j = rem - r * 10;
    const float* tin = half ? p.t_y : p.t_x;
    float a = p.mb1[j];
    for (int k = 0; k < 60; ++k) a += tin[(size_t)r * 60 + k] * p.mW1[k * 10 + j];
    p.hidb[idx] = a;
  }
  for (int idx = id; idx < 409600; idx += nt) {
    int c = idx / 6400, r2 = idx - c * 6400;
    int n = r2 >> 3, d = r2 & 7;
    p.Wat[idx] = p.Wa[((size_t)n * 64 + c) * 8 + d];
  }
}

// T2h = 2*G@G - I (f16), plus mlp_out
__global__ void __launch_bounds__(256) k_pre1(Params p) {
  __shared__ float As[16 * 68];
  __shared__ float Bs[16 * 68];
  int tid = threadIdx.x, tx = tid & 15, ty = tid >> 4;
  const float* A = p.G;
  for (int tile = blockIdx.x; tile < 169; tile += gridDim.x) {
    int bx = tile % 13, by = tile / 13;
    int rowBase = by * 64, colBase = bx * 64;
    float acc[4][4] = {};
    for (int k0 = 0; k0 < 800; k0 += 16) {
      __syncthreads();
      for (int e = tid; e < 1024; e += 256) {
        int r = e >> 4, c = e & 15;
        int gr = rowBase + r;
        As[c * 68 + r] = (gr < 800) ? A[gr * 800 + k0 + c] : 0.f;
      }
      for (int e = tid; e < 1024; e += 256) {
        int r = e >> 6, c = e & 63;
        int gc = colBase + c;
        Bs[r * 68 + c] = (gc < 800) ? A[(k0 + r) * 800 + gc] : 0.f;
      }
      __syncthreads();
#pragma unroll
      for (int kk = 0; kk < 16; ++kk) {
        float4 a4 = *(const float4*)&As[kk * 68 + ty * 4];
        float4 b4 = *(const float4*)&Bs[kk * 68 + tx * 4];
        float av[4] = {a4.x, a4.y, a4.z, a4.w};
        float bv[4] = {b4.x, b4.y, b4.z, b4.w};
#pragma unroll
        for (int i = 0; i < 4; ++i)
#pragma unroll
          for (int j = 0; j < 4; ++j) acc[i][j] += av[i] * bv[j];
      }
    }
#pragma unroll
    for (int i = 0; i < 4; ++i) {
      int m = rowBase + ty * 4 + i;
      if (m >= 800) continue;
#pragma unroll
      for (int j = 0; j < 4; ++j) {
        int n = colBase + tx * 4 + j;
        if (n < 800) p.T2h[(size_t)m * 800 + n] = (f16_t)(2.f * acc[i][j] - (m == n ? 1.f : 0.f));
      }
    }
  }
  int nt = gridDim.x * blockDim.x, id = blockIdx.x * blockDim.x + threadIdx.x;
  for (int idx = id; idx < 2 * 768 * 1600; idx += nt) {
    int half = idx / (768 * 1600), rem = idx - half * (768 * 1600);
    int r = rem / 1600, o = rem - r * 1600;
    const float* hid = p.hidb + half * 7680;
    float* emb = half ? p.tye : p.txe;
    float a = p.mb2[o];
#pragma unroll
    for (int k = 0; k < 10; ++k) a += hid[r * 10 + k] * p.mW2[k * 1600 + o];
    emb[rem] = a;
  }
}

// Bpk[nT][ks][kg][col][8]: value Bstk[k'][n], k' = ks*32+kg*8+e, n = nT*128+col; zero-pad n>=800
__global__ void __launch_bounds__(256) k_pre2(Params p) {
  int nt = gridDim.x * blockDim.x, id = blockIdx.x * blockDim.x + threadIdx.x;
  for (int idx = id; idx < 7 * 50 * 4096; idx += nt) {
    int nT = idx / 204800, rem = idx - nT * 204800;
    int ks = rem >> 12, i = rem & 4095;
    int kg = i >> 10, col = (i >> 3) & 127, e = i & 7;
    int k = ks * 32 + kg * 8 + e;
    int n = nT * 128 + col;
    f16_t v = (f16_t)0.f;
    if (n < 800) v = (k < 800) ? (f16_t)p.G[(size_t)k * 800 + n] : p.T2h[(size_t)(k - 800) * 800 + n];
    p.Bpk[idx] = v;
  }
}

// ================= gate small proj: Y_s[c][n] = sum_c' wsp[s][c][c'] * X[c'][n] =================
template <int LAYER>
__global__ void __launch_bounds__(256, 3) g_small(Params p, int widx, int dec, int t) {
  __shared__ f16_t XS[128 * 136];
  unsigned* XS32 = (unsigned*)XS;
  int tid = threadIdx.x, lane = tid & 63, wid = tid >> 6;
  int lrow = lane & 15, lgrp = lane >> 4;
  int wm = wid >> 1, wn = wid & 1;
  int swz = xcd_swz(blockIdx.x, gridDim.x);
  int b = swz / 7, nBase = (swz % 7) * 128;
  const f16_t* __restrict__ wb = p.wsp[widx];
  const float* emb = dec ? p.tye : p.txe;

  {
    int rp = tid >> 3, n0 = (tid & 7) * 16;
    int ng = nBase + n0;
    bool nval = ng < 800;
    for (int pass = 0; pass < 2; ++pass) {
      float v[2][16];
#pragma unroll
      for (int par = 0; par < 2; ++par) {
        int cp = pass * 64 + 2 * rp + par;
        float* vv = v[par];
        if (!nval) {
#pragma unroll
          for (int i = 0; i < 16; ++i) vv[i] = 0.f;
        } else if (LAYER == 1) {
          const float* src = (cp < 64) ? p.h0 + ((size_t)(b * 64 + cp)) * 800 + ng
                                       : p.h1 + ((size_t)(b * 64 + cp - 64)) * 800 + ng;
#pragma unroll
          for (int q = 0; q < 4; ++q) {
            float4 f = *(const float4*)(src + q * 4);
            vv[q * 4 + 0] = f.x; vv[q * 4 + 1] = f.y; vv[q * 4 + 2] = f.z; vv[q * 4 + 3] = f.w;
          }
        } else {
          if (cp >= 68) {
#pragma unroll
            for (int i = 0; i < 16; ++i) vv[i] = 0.f;
          } else if (cp >= 4) {
            const float* src = p.h0 + ((size_t)(b * 64 + cp - 4)) * 800 + ng;
#pragma unroll
            for (int q = 0; q < 4; ++q) {
              float4 f = *(const float4*)(src + q * 4);
              vv[q * 4 + 0] = f.x; vv[q * 4 + 1] = f.y; vv[q * 4 + 2] = f.z; vv[q * 4 + 3] = f.w;
            }
          } else if (cp >= 2) {
#pragma unroll
            for (int i = 0; i < 16; ++i)
              vv[i] = emb[(size_t)(b * 12 + t) * 1600 + (ng + i) * 2 + (cp - 2)];
          } else {
            if (dec) {
              if (t == 0) {
#pragma unroll
                for (int i = 0; i < 16; ++i) vv[i] = 0.f;
              } else {
#pragma unroll
                for (int i = 0; i < 16; ++i)
                  vv[i] = p.dout[((size_t)(b * 12 + t - 1) * 800 + ng + i) * 2 + cp];
              }
            } else {
#pragma unroll
              for (int i = 0; i < 16; ++i)
                vv[i] = p.x_seq[((size_t)(b * 12 + t) * 800 + ng + i) * 2 + cp];
            }
          }
        }
      }
#pragma unroll
      for (int i = 0; i < 16; ++i) {
        union { f16_t h[2]; unsigned u; } pk;
        pk.h[0] = (f16_t)v[0][i];
        pk.h[1] = (f16_t)v[1][i];
        XS32[(n0 + i) * 68 + pass * 32 + rp] = pk.u;
      }
    }
  }
  __syncthreads();

  for (int s = 0; s < 3; ++s) {
    f32x4 acc[4][4];
#pragma unroll
    for (int i = 0; i < 4; ++i)
#pragma unroll
      for (int j = 0; j < 4; ++j) acc[i][j] = (f32x4){0.f, 0.f, 0.f, 0.f};
#pragma unroll
    for (int ks = 0; ks < 4; ++ks) {
      half8 fa[4], fx[4];
#pragma unroll
      for (int mf = 0; mf < 4; ++mf)
        fa[mf] = *(const half8*)(wb + ((size_t)(s * 128 + wm * 64 + mf * 16 + lrow) << 7) + ks * 32 + lgrp * 8);
#pragma unroll
      for (int nt = 0; nt < 4; ++nt)
        fx[nt] = *(const half8*)(XS + (wn * 64 + nt * 16 + lrow) * 136 + ks * 32 + lgrp * 8);
#pragma unroll
      for (int mf = 0; mf < 4; ++mf)
#pragma unroll
        for (int nt = 0; nt < 4; ++nt)
          acc[mf][nt] = __builtin_amdgcn_mfma_f32_16x16x32_f16(fa[mf], fx[nt], acc[mf][nt], 0, 0, 0);
    }
#pragma unroll
    for (int mf = 0; mf < 4; ++mf)
#pragma unroll
      for (int nt = 0; nt < 4; ++nt) {
        int n = nBase + wn * 64 + nt * 16 + lrow;
        if (n >= 800) continue;
#pragma unroll
        for (int j = 0; j < 4; ++j) {
          int c = wm * 64 + mf * 16 + lgrp * 4 + j;
          size_t r = (size_t)(b * 128 + c);
          f16_t val = (f16_t)acc[mf][nt][j];
          if (s == 0) {
            p.Y0g[r * 800 + n] = val;
          } else {
            int kp = (s - 1) * 800 + n;
            p.Ybg[((size_t)(kp >> 3) * 8192 + r) * 8 + (kp & 7)] = val;
          }
        }
      }
  }
}

// ================= gate big GEMM (M=8192) + fused CAND small-proj in rh-half blocks =========
template <int LAYER>
__global__ void __launch_bounds__(256, 4) g_biggate(Params p, int w0, int dec, int t, float* hcur) {
  constexpr int Pin = LAYER ? 64 : 4;
  __shared__ __align__(16) f16_t SH[18432];
  f16_t* AS = SH;
  f16_t* BS = SH + 6144;
  int tid = threadIdx.x, lane = tid & 63, w = tid >> 6;
  int lrow = lane & 15, lgrp = lane >> 4;
  int wm = w >> 1, wn = w & 1;
  int swz = xcd_swz(blockIdx.x, gridDim.x);
  int rt = swz / 7;
  int rBase = rt * 64;
  int nTile = swz % 7;
  int b = rt >> 1;
  int rhblk = rt & 1;
  const f16_t* __restrict__ Abase = p.Ybg;
  const f16_t* __restrict__ Bbase = p.Bpk + (size_t)nTile * 204800;
  const float* bias = p.bia[w0];

  auto stage = [&](int buf, int ks) {
    gload16(Abase + ((size_t)(ks * 4 + w) * 8192 + rBase + lane) * 8, AS + buf * 2048 + w * 512);
    gload16(Bbase + (size_t)ks * 4096 + (size_t)(w * 2 + 0) * 512 + lane * 8, BS + buf * 4096 + (w * 2 + 0) * 512);
    gload16(Bbase + (size_t)ks * 4096 + (size_t)(w * 2 + 1) * 512 + lane * 8, BS + buf * 4096 + (w * 2 + 1) * 512);
  };

  f32x4 acc[2][4];
#pragma unroll
  for (int i = 0; i < 2; ++i)
#pragma unroll
    for (int j = 0; j < 4; ++j) acc[i][j] = (f32x4){0.f, 0.f, 0.f, 0.f};

  stage(0, 0);
  stage(1, 1);
  for (int ks = 0; ks < 50; ++ks) {
    if (ks == 49) {
      asm volatile("s_waitcnt vmcnt(0)" ::: "memory");
    } else {
      asm volatile("s_waitcnt vmcnt(3)" ::: "memory");
    }
    __builtin_amdgcn_s_barrier();
    __builtin_amdgcn_sched_barrier(0);
    if (ks + 2 < 50) stage((ks + 2) % 3, ks + 2);  // issue-early prefetch
    int cur = ks % 3;
    half8 fa[2], fb[4];
#pragma unroll
    for (int mt = 0; mt < 2; ++mt)
      fa[mt] = *(const half8*)(AS + cur * 2048 + lgrp * 512 + (wm * 32 + mt * 16 + lrow) * 8);
#pragma unroll
    for (int nt = 0; nt < 4; ++nt)
      fb[nt] = *(const half8*)(BS + cur * 4096 + lgrp * 1024 + (wn * 64 + nt * 16 + lrow) * 8);
#pragma unroll
    for (int mt = 0; mt < 2; ++mt)
#pragma unroll
      for (int nt = 0; nt < 4; ++nt)
        acc[mt][nt] = __builtin_amdgcn_mfma_f32_16x16x32_f16(fa[mt], fb[nt], acc[mt][nt], 0, 0, 0);
  }

  if (!rhblk) {
#pragma unroll
    for (int mt = 0; mt < 2; ++mt)
#pragma unroll
      for (int nt = 0; nt < 4; ++nt) {
        int n = nTile * 128 + wn * 64 + nt * 16 + lrow;
        if (n >= 800) continue;
#pragma unroll
        for (int j = 0; j < 4; ++j) {
          int c = wm * 32 + mt * 16 + lgrp * 4 + j;
          int r = rBase + c;
          float v = acc[mt][nt][j] + (float)p.Y0g[(size_t)r * 800 + n] + bias[c];
          p.Uh[(size_t)(b * 64 + c) * 800 + n] = (f16_t)sigm(v);
        }
      }
    return;
  }

  f16_t rhv[2][4][4];
#pragma unroll
  for (int mt = 0; mt < 2; ++mt)
#pragma unroll
    for (int nt = 0; nt < 4; ++nt) {
      int n = nTile * 128 + wn * 64 + nt * 16 + lrow;
#pragma unroll
      for (int j = 0; j < 4; ++j) {
        int jj = wm * 32 + mt * 16 + lgrp * 4 + j;
        if (n < 800) {
          int r = rBase + jj;
          float v = acc[mt][nt][j] + (float)p.Y0g[(size_t)r * 800 + n] + bias[64 + jj];
          float hv = hcur[(size_t)(b * 64 + jj) * 800 + n];
          rhv[mt][nt][j] = (f16_t)(sigm(v) * hv);
        } else {
          rhv[mt][nt][j] = (f16_t)0.f;
        }
      }
    }

  __syncthreads();
  f16_t* Xc = SH;

#pragma unroll
  for (int mt = 0; mt < 2; ++mt)
#pragma unroll
    for (int nt = 0; nt < 4; ++nt) {
      int col = wn * 64 + nt * 16 + lrow;
#pragma unroll
      for (int j = 0; j < 4; ++j) {
        int jj = wm * 32 + mt * 16 + lgrp * 4 + j;
        Xc[col * 136 + Pin + jj] = rhv[mt][nt][j];
      }
    }
  if (LAYER == 1) {
    int ct = tid >> 2, nq = tid & 3;
    const float* src = p.h0 + (size_t)(b * 64 + ct) * 800;
#pragma unroll 8
    for (int i = 0; i < 32; ++i) {
      int nl = nq * 32 + i;
      int n = nTile * 128 + nl;
      float v = (n < 800) ? src[n] : 0.f;
      Xc[nl * 136 + ct] = (f16_t)v;
    }
  } else {
    if (tid < 128) {
      int col = tid;
      int n = nTile * 128 + col;
      float v0 = 0.f, v1 = 0.f, v2 = 0.f, v3 = 0.f;
      if (n < 800) {
        if (dec) {
          if (t > 0) {
            v0 = p.dout[((size_t)(b * 12 + t - 1) * 800 + n) * 2 + 0];
            v1 = p.dout[((size_t)(b * 12 + t - 1) * 800 + n) * 2 + 1];
          }
        } else {
          v0 = p.x_seq[((size_t)(b * 12 + t) * 800 + n) * 2 + 0];
          v1 = p.x_seq[((size_t)(b * 12 + t) * 800 + n) * 2 + 1];
        }
        const float* emb = dec ? p.tye : p.txe;
        v2 = emb[(size_t)(b * 12 + t) * 1600 + n * 2 + 0];
        v3 = emb[(size_t)(b * 12 + t) * 1600 + n * 2 + 1];
      }
      Xc[col * 136 + 0] = (f16_t)v0;
      Xc[col * 136 + 1] = (f16_t)v1;
      Xc[col * 136 + 2] = (f16_t)v2;
      Xc[col * 136 + 3] = (f16_t)v3;
      unsigned* z32 = (unsigned*)(Xc + col * 136 + 68);
#pragma unroll
      for (int q = 0; q < 30; ++q) z32[q] = 0u;
    }
  }
  __syncthreads();

  const f16_t* __restrict__ wc = p.wsp[w0 + 1];
  int cwn = w;
  for (int s = 0; s < 3; ++s) {
    f32x4 ac[4][2];
#pragma unroll
    for (int i = 0; i < 4; ++i)
#pragma unroll
      for (int j = 0; j < 2; ++j) ac[i][j] = (f32x4){0.f, 0.f, 0.f, 0.f};
#pragma unroll
    for (int ks = 0; ks < 4; ++ks) {
      half8 fa[4], fx[2];
#pragma unroll
      for (int mf = 0; mf < 4; ++mf)
        fa[mf] = *(const half8*)(wc + ((size_t)(s * 64 + mf * 16 + lrow) << 7) + ks * 32 + lgrp * 8);
#pragma unroll
      for (int nt = 0; nt < 2; ++nt)
        fx[nt] = *(const half8*)(Xc + (cwn * 32 + nt * 16 + lrow) * 136 + ks * 32 + lgrp * 8);
#pragma unroll
      for (int mf = 0; mf < 4; ++mf)
#pragma unroll
        for (int nt = 0; nt < 2; ++nt)
          ac[mf][nt] = __builtin_amdgcn_mfma_f32_16x16x32_f16(fa[mf], fx[nt], ac[mf][nt], 0, 0, 0);
    }
#pragma unroll
    for (int mf = 0; mf < 4; ++mf)
#pragma unroll
      for (int nt = 0; nt < 2; ++nt) {
        int n = nTile * 128 + cwn * 32 + nt * 16 + lrow;
        if (n >= 800) continue;
#pragma unroll
        for (int j = 0; j < 4; ++j) {
          int c = mf * 16 + lgrp * 4 + j;
          size_t r = (size_t)(b * 64 + c);
          f16_t val = (f16_t)ac[mf][nt][j];
          if (s == 0) {
            p.Y0c[r * 800 + n] = val;
          } else {
            int kp = (s - 1) * 800 + n;
            p.Ybc[((size_t)(kp >> 3) * 4096 + r) * 8 + (kp & 7)] = val;
          }
        }
      }
  }
}

// ================= cand big GEMM (M=4096), GRU h-update epilogue =================
__global__ void __launch_bounds__(256, 4) g_bigcand(Params p, int widx, float* hcur) {
  __shared__ __align__(16) f16_t SH[18432];
  f16_t* AS = SH;
  f16_t* BS = SH + 6144;
  int tid = threadIdx.x, lane = tid & 63, w = tid >> 6;
  int lrow = lane & 15, lgrp = lane >> 4;
  int wm = w >> 1, wn = w & 1;
  int swz = xcd_swz(blockIdx.x, gridDim.x);
  int rBase = (swz / 7) * 64;
  int nTile = swz % 7;
  const f16_t* __restrict__ Abase = p.Ybc;
  const f16_t* __restrict__ Bbase = p.Bpk + (size_t)nTile * 204800;
  const float* bias = p.bia[widx];

  auto stage = [&](int buf, int ks) {
    gload16(Abase + ((size_t)(ks * 4 + w) * 4096 + rBase + lane) * 8, AS + buf * 2048 + w * 512);
    gload16(Bbase + (size_t)ks * 4096 + (size_t)(w * 2 + 0) * 512 + lane * 8, BS + buf * 4096 + (w * 2 + 0) * 512);
    gload16(Bbase + (size_t)ks * 4096 + (size_t)(w * 2 + 1) * 512 + lane * 8, BS + buf * 4096 + (w * 2 + 1) * 512);
  };

  f32x4 acc[2][4];
#pragma unroll
  for (int i = 0; i < 2; ++i)
#pragma unroll
    for (int j = 0; j < 4; ++j) acc[i][j] = (f32x4){0.f, 0.f, 0.f, 0.f};

  stage(0, 0);
  stage(1, 1);
  for (int ks = 0; ks < 50; ++ks) {
    if (ks == 49) {
      asm volatile("s_waitcnt vmcnt(0)" ::: "memory");
    } else {
      asm volatile("s_waitcnt vmcnt(3)" ::: "memory");
    }
    __builtin_amdgcn_s_barrier();
    __builtin_amdgcn_sched_barrier(0);
    if (ks + 2 < 50) stage((ks + 2) % 3, ks + 2);  // issue-early prefetch
    int cur = ks % 3;
    half8 fa[2], fb[4];
#pragma unroll
    for (int mt = 0; mt < 2; ++mt)
      fa[mt] = *(const half8*)(AS + cur * 2048 + lgrp * 512 + (wm * 32 + mt * 16 + lrow) * 8);
#pragma unroll
    for (int nt = 0; nt < 4; ++nt)
      fb[nt] = *(const half8*)(BS + cur * 4096 + lgrp * 1024 + (wn * 64 + nt * 16 + lrow) * 8);
#pragma unroll
    for (int mt = 0; mt < 2; ++mt)
#pragma unroll
      for (int nt = 0; nt < 4; ++nt)
        acc[mt][nt] = __builtin_amdgcn_mfma_f32_16x16x32_f16(fa[mt], fb[nt], acc[mt][nt], 0, 0, 0);
  }

#pragma unroll
  for (int mt = 0; mt < 2; ++mt)
#pragma unroll
    for (int nt = 0; nt < 4; ++nt) {
      int n = nTile * 128 + wn * 64 + nt * 16 + lrow;
      if (n >= 800) continue;
#pragma unroll
      for (int j = 0; j < 4; ++j) {
        int r = rBase + wm * 32 + mt * 16 + lgrp * 4 + j;
        int b = r >> 6, c = r & 63;
        float v = acc[mt][nt][j] + (float)p.Y0c[(size_t)r * 800 + n] + bias[c];
        float u = (float)p.Uh[(size_t)(b * 64 + c) * 800 + n];
        float hv = hcur[(size_t)(b * 64 + c) * 800 + n];
        hcur[(size_t)(b * 64 + c) * 800 + n] = (1.f - u) * hv + u * tanhf(v);
      }
    }
}

// ================= attention: split-K q reduce, then softmax+outproj =================

__global__ void __launch_bounds__(256) k_att1(Params p) {
  int gwid = (blockIdx.x * blockDim.x + threadIdx.x) >> 6;
  int nw = (gridDim.x * blockDim.x) >> 6;
  int lane = threadIdx.x & 63;
  for (int tile = gwid; tile < 1024; tile += nw) {
    int cx = tile & 15, b = tile >> 4;
    float acc[8] = {};
    const float* hrow = p.h1 + (size_t)b * 51200 + cx * 3200;
    const float* wbase = p.Wat + (size_t)cx * 3200 * 8;
    for (int i = lane; i < 3200; i += 64) {
      float hv = hrow[i];
      const float* wr = wbase + (size_t)i * 8;
#pragma unroll
      for (int j = 0; j < 8; ++j) acc[j] += hv * wr[j];
    }
#pragma unroll
    for (int s = 1; s < 64; s <<= 1) {
#pragma unroll
      for (int j = 0; j < 8; ++j) acc[j] += __shfl_xor(acc[j], s);
    }
    if (lane == 0) {
#pragma unroll
      for (int j = 0; j < 8; ++j) p.partial[((size_t)b * 16 + cx) * 8 + j] = acc[j];
    }
  }
}

__global__ void __launch_bounds__(256) k_att2(Params p, int t) {
  int b = blockIdx.x >> 2, q4 = blockIdx.x & 3;
  int tid = threadIdx.x;
  float qv[8] = {};
  for (int cx = 0; cx < 16; ++cx)
#pragma unroll
    for (int j = 0; j < 8; ++j) qv[j] += p.partial[((size_t)b * 16 + cx) * 8 + j];
  float sco[4], mx = -1e30f;
#pragma unroll
  for (int m = 0; m < 4; ++m) {
    float s = 0.f;
#pragma unroll
    for (int d = 0; d < 8; ++d) s += qv[d] * p.mem[m * 8 + d];
    sco[m] = s;
    mx = fmaxf(mx, s);
  }
  float se = 0.f;
#pragma unroll
  for (int m = 0; m < 4; ++m) { sco[m] = expf(sco[m] - mx); se += sco[m]; }
  float attv[8];
#pragma unroll
  for (int d = 0; d < 8; ++d) {
    float av = 0.f;
#pragma unroll
    for (int m = 0; m < 4; ++m) av += (sco[m] / se) * p.mem[m * 8 + d];
    attv[d] = av;
  }
  if (tid >= 200) return;
  int n = q4 * 200 + tid;
  float attm[8];
#pragma unroll
  for (int d = 0; d < 8; ++d) {
    float s = 0.f;
#pragma unroll
    for (int m = 0; m < 8; ++m) s += attv[m] * p.fc[(size_t)m * 6400 + n * 8 + d];
    attm[d] = s;
  }
  float o0 = p.projb[0], o1 = p.projb[1];
  const float* hb = p.h1 + (size_t)b * 51200 + n;
#pragma unroll 16
  for (int j = 0; j < 64; ++j) {
    float hv = hb[(size_t)j * 800];
    o0 += hv * p.projW[j * 2 + 0];
    o1 += hv * p.projW[j * 2 + 1];
  }
#pragma unroll
  for (int d = 0; d < 8; ++d) {
    o0 += attm[d] * p.projW[(64 + d) * 2 + 0];
    o1 += attm[d] * p.projW[(64 + d) * 2 + 1];
  }
  size_t base = ((size_t)(b * 12 + t) * 800 + n) * 2;
  p.dout[base + 0] = fmaxf(o0, 0.f);
  p.dout[base + 1] = fmaxf(o1, 0.f);
}

// ================= host =================

extern "C" void kernel_launch(void* const* d_in, const int* in_sizes, int n_in,
                              void* d_out, int out_size, void* d_ws, size_t ws_size,
                              hipStream_t stream) {
  Params P;
  P.x_seq = (const float*)d_in[0];
  P.t_x = (const float*)d_in[1];
  P.t_y = (const float*)d_in[2];
  P.G = (const float*)d_in[3];
  P.Wraw[0] = (const float*)d_in[4];  P.bia[0] = (const float*)d_in[5];
  P.Wraw[1] = (const float*)d_in[6];  P.bia[1] = (const float*)d_in[7];
  P.Wraw[2] = (const float*)d_in[8];  P.bia[2] = (const float*)d_in[9];
  P.Wraw[3] = (const float*)d_in[10]; P.bia[3] = (const float*)d_in[11];
  P.Wraw[4] = (const float*)d_in[12]; P.bia[4] = (const float*)d_in[13];
  P.Wraw[5] = (const float*)d_in[14]; P.bia[5] = (const float*)d_in[15];
  P.Wraw[6] = (const float*)d_in[16]; P.bia[6] = (const float*)d_in[17];
  P.Wraw[7] = (const float*)d_in[18]; P.bia[7] = (const float*)d_in[19];
  P.mW1 = (const float*)d_in[20];
  P.mb1 = (const float*)d_in[21];
  P.mW2 = (const float*)d_in[22];
  P.mb2 = (const float*)d_in[23];
  P.mem = (const float*)d_in[24];
  P.Wa = (const float*)d_in[25];
  P.fc = (const float*)d_in[26];
  P.projW = (const float*)d_in[27];
  P.projb = (const float*)d_in[28];
  P.dout = (float*)d_out;

  float* ws = (float*)d_ws;
  size_t off = 0;
  auto alloc = [&](size_t nel) { float* q = ws + off; off += (nel + 3) & ~(size_t)3; return q; };
  P.T2h = (f16_t*)alloc(320000);
  P.Bpk = (f16_t*)alloc((size_t)7 * 50 * 4096 / 2);
  P.Y0g = (f16_t*)alloc((size_t)8192 * 800 / 2);
  P.Ybg = (f16_t*)alloc((size_t)1600 * 8192 / 2);
  P.Y0c = (f16_t*)alloc((size_t)4096 * 800 / 2);
  P.Ybc = (f16_t*)alloc((size_t)1600 * 4096 / 2);
  P.Uh = (f16_t*)alloc((size_t)4096 * 800 / 2);
  P.h0 = alloc((size_t)4096 * 800);
  P.h1 = alloc((size_t)4096 * 800);
  P.txe = alloc((size_t)768 * 1600);
  P.tye = alloc((size_t)768 * 1600);
  P.hidb = alloc(15360);
  P.partial = alloc(8192);
  P.Wat = alloc(409600);
  for (int w = 0; w < 8; ++w) {
    int cand = w & 1;
    int NC = cand ? 64 : 128;
    P.wsp[w] = (f16_t*)alloc((size_t)3 * NC * 128 / 2);
  }

  k_pre0<<<512, 256, 0, stream>>>(P);
  k_pre1<<<512, 256, 0, stream>>>(P);
  k_pre2<<<512, 256, 0, stream>>>(P);

  auto cell = [&](int dec, int t) {
    int w0 = dec * 4;
    // ---- layer 0 ----
    g_small<0><<<448, 256, 0, stream>>>(P, w0 + 0, dec, t);
    g_biggate<0><<<896, 256, 0, stream>>>(P, w0 + 0, dec, t, P.h0);
    g_bigcand<<<448, 256, 0, stream>>>(P, w0 + 1, P.h0);
    // ---- layer 1 ----
    g_small<1><<<448, 256, 0, stream>>>(P, w0 + 2, dec, t);
    g_biggate<1><<<896, 256, 0, stream>>>(P, w0 + 2, dec, t, P.h1);
    g_bigcand<<<448, 256, 0, stream>>>(P, w0 + 3, P.h1);
  };

  for (int t = 0; t < 12; ++t) cell(0, t);
  for (int t = 0; t < 12; ++t) {
    cell(1, t);
    k_att1<<<256, 256, 0, stream>>>(P);
    k_att2<<<256, 256, 0, stream>>>(P, t);
  }
}

// Round 16
// 6464.701 us; speedup vs baseline: 1.1351x; 1.0205x over previous
//
#include <hip/hip_runtime.h>
#include <math.h>

typedef _Float16 f16_t;
typedef _Float16 half8 __attribute__((ext_vector_type(8)));
typedef float f32x4 __attribute__((ext_vector_type(4)));

// small-proj first: Y_k = W_k^T (.) X (K=128); then big GEMM out = Y0 + [Y1|Y2] @ [G;T2] (K=1600).
// biggate fuses CAND small-proj in rh-half blocks. Encoder is software-pipelined across layers:
// each phase dispatch runs L0(t) and L1(t-1) jobs concurrently (independent), buffers per layer.

struct Params {
  const float *x_seq, *t_x, *t_y, *G;
  const float *Wraw[8], *bia[8];  // idx = dec*4 + layer*2 + cand
  const float *mW1, *mb1, *mW2, *mb2, *mem, *Wa, *fc, *projW, *projb;
  float* dout;
  float *h0, *h1, *txe, *tye, *hidb, *partial, *Wat;
  f16_t *T2h, *Bpk;
  f16_t *Y0gL[2], *YbgL[2], *Y0cL[2], *YbcL[2], *UhL[2];
  f16_t* wsp[8];  // [3][NC][128] folded, transposed, f16
};

__device__ __forceinline__ float sigm(float x) { return 1.0f / (1.0f + expf(-x)); }

__device__ __forceinline__ int xcd_swz(int orig, int nwg) {
  int q = nwg >> 3, r = nwg & 7, xcd = orig & 7, j = orig >> 3;
  return (xcd < r ? xcd * (q + 1) : r * (q + 1) + (xcd - r) * q) + j;
}

__device__ __forceinline__ void gload16(const void* g, void* l) {
  __builtin_amdgcn_global_load_lds((const __attribute__((address_space(1))) void*)g,
                                   (__attribute__((address_space(3))) void*)l, 16, 0, 0);
}

// ================= prologue =================

__global__ void __launch_bounds__(256) k_pre0(Params p) {
  int nt = gridDim.x * blockDim.x, id = blockIdx.x * blockDim.x + threadIdx.x;
  float4 z = {0.f, 0.f, 0.f, 0.f};
  for (int i = id; i < 64 * 64 * 200; i += nt) { ((float4*)p.h0)[i] = z; ((float4*)p.h1)[i] = z; }
  for (int w = 0; w < 8; ++w) {
    int layer = (w >> 1) & 1, cand = w & 1;
    int P = layer ? 128 : 68, NC = cand ? 64 : 128;
    const float* W = p.Wraw[w];
    f16_t* dst = p.wsp[w];
    int tot = 3 * NC * 128;
    for (int idx = id; idx < tot; idx += nt) {
      int s = idx / (NC * 128), rem = idx - s * (NC * 128);
      int c = rem >> 7, pp = rem & 127;
      float v = 0.f;
      if (pp < P) {
        if (s == 0)
          v = W[(size_t)pp * NC + c] + 0.05f * (W[(size_t)(P + pp) * NC + c] + W[(size_t)(2 * P + pp) * NC + c]);
        else
          v = 0.95f * W[(size_t)(s * P + pp) * NC + c];
      }
      dst[idx] = (f16_t)v;
    }
  }
  for (int idx = id; idx < 15360; idx += nt) {
    int half = idx / 7680, rem = idx - half * 7680;
    int r = rem / 10, j = rem - r * 10;
    const float* tin = half ? p.t_y : p.t_x;
    float a = p.mb1[j];
    for (int k = 0; k < 60; ++k) a += tin[(size_t)r * 60 + k] * p.mW1[k * 10 + j];
    p.hidb[idx] = a;
  }
  for (int idx = id; idx < 409600; idx += nt) {
    int c = idx / 6400, r2 = idx - c * 6400;
    int n = r2 >> 3, d = r2 & 7;
    p.Wat[idx] = p.Wa[((size_t)n * 64 + c) * 8 + d];
  }
}

// T2h = 2*G@G - I (f16), plus mlp_out
__global__ void __launch_bounds__(256) k_pre1(Params p) {
  __shared__ float As[16 * 68];
  __shared__ float Bs[16 * 68];
  int tid = threadIdx.x, tx = tid & 15, ty = tid >> 4;
  const float* A = p.G;
  for (int tile = blockIdx.x; tile < 169; tile += gridDim.x) {
    int bx = tile % 13, by = tile / 13;
    int rowBase = by * 64, colBase = bx * 64;
    float acc[4][4] = {};
    for (int k0 = 0; k0 < 800; k0 += 16) {
      __syncthreads();
      for (int e = tid; e < 1024; e += 256) {
        int r = e >> 4, c = e & 15;
        int gr = rowBase + r;
        As[c * 68 + r] = (gr < 800) ? A[gr * 800 + k0 + c] : 0.f;
      }
      for (int e = tid; e < 1024; e += 256) {
        int r = e >> 6, c = e & 63;
        int gc = colBase + c;
        Bs[r * 68 + c] = (gc < 800) ? A[(k0 + r) * 800 + gc] : 0.f;
      }
      __syncthreads();
#pragma unroll
      for (int kk = 0; kk < 16; ++kk) {
        float4 a4 = *(const float4*)&As[kk * 68 + ty * 4];
        float4 b4 = *(const float4*)&Bs[kk * 68 + tx * 4];
        float av[4] = {a4.x, a4.y, a4.z, a4.w};
        float bv[4] = {b4.x, b4.y, b4.z, b4.w};
#pragma unroll
        for (int i = 0; i < 4; ++i)
#pragma unroll
          for (int j = 0; j < 4; ++j) acc[i][j] += av[i] * bv[j];
      }
    }
#pragma unroll
    for (int i = 0; i < 4; ++i) {
      int m = rowBase + ty * 4 + i;
      if (m >= 800) continue;
#pragma unroll
      for (int j = 0; j < 4; ++j) {
        int n = colBase + tx * 4 + j;
        if (n < 800) p.T2h[(size_t)m * 800 + n] = (f16_t)(2.f * acc[i][j] - (m == n ? 1.f : 0.f));
      }
    }
  }
  int nt = gridDim.x * blockDim.x, id = blockIdx.x * blockDim.x + threadIdx.x;
  for (int idx = id; idx < 2 * 768 * 1600; idx += nt) {
    int half = idx / (768 * 1600), rem = idx - half * (768 * 1600);
    int r = rem / 1600, o = rem - r * 1600;
    const float* hid = p.hidb + half * 7680;
    float* emb = half ? p.tye : p.txe;
    float a = p.mb2[o];
#pragma unroll
    for (int k = 0; k < 10; ++k) a += hid[r * 10 + k] * p.mW2[k * 1600 + o];
    emb[rem] = a;
  }
}

// Bpk[nT][ks][kg][col][8]
__global__ void __launch_bounds__(256) k_pre2(Params p) {
  int nt = gridDim.x * blockDim.x, id = blockIdx.x * blockDim.x + threadIdx.x;
  for (int idx = id; idx < 7 * 50 * 4096; idx += nt) {
    int nT = idx / 204800, rem = idx - nT * 204800;
    int ks = rem >> 12, i = rem & 4095;
    int kg = i >> 10, col = (i >> 3) & 127, e = i & 7;
    int k = ks * 32 + kg * 8 + e;
    int n = nT * 128 + col;
    f16_t v = (f16_t)0.f;
    if (n < 800) v = (k < 800) ? (f16_t)p.G[(size_t)k * 800 + n] : p.T2h[(size_t)(k - 800) * 800 + n];
    p.Bpk[idx] = v;
  }
}

// ================= gate small proj body =================
template <int LAYER>
__device__ void small_body(const Params& p, char* smraw, int widx, int dec, int t,
                           f16_t* __restrict__ Y0g, f16_t* __restrict__ Ybg, int lblk) {
  f16_t* XS = (f16_t*)smraw;
  unsigned* XS32 = (unsigned*)smraw;
  int tid = threadIdx.x, lane = tid & 63, wid = tid >> 6;
  int lrow = lane & 15, lgrp = lane >> 4;
  int wm = wid >> 1, wn = wid & 1;
  int swz = xcd_swz(lblk, 448);
  int b = swz / 7, nBase = (swz % 7) * 128;
  const f16_t* __restrict__ wb = p.wsp[widx];
  const float* emb = dec ? p.tye : p.txe;

  {
    int rp = tid >> 3, n0 = (tid & 7) * 16;
    int ng = nBase + n0;
    bool nval = ng < 800;
    for (int pass = 0; pass < 2; ++pass) {
      float v[2][16];
#pragma unroll
      for (int par = 0; par < 2; ++par) {
        int cp = pass * 64 + 2 * rp + par;
        float* vv = v[par];
        if (!nval) {
#pragma unroll
          for (int i = 0; i < 16; ++i) vv[i] = 0.f;
        } else if (LAYER == 1) {
          const float* src = (cp < 64) ? p.h0 + ((size_t)(b * 64 + cp)) * 800 + ng
                                       : p.h1 + ((size_t)(b * 64 + cp - 64)) * 800 + ng;
#pragma unroll
          for (int q = 0; q < 4; ++q) {
            float4 f = *(const float4*)(src + q * 4);
            vv[q * 4 + 0] = f.x; vv[q * 4 + 1] = f.y; vv[q * 4 + 2] = f.z; vv[q * 4 + 3] = f.w;
          }
        } else {
          if (cp >= 68) {
#pragma unroll
            for (int i = 0; i < 16; ++i) vv[i] = 0.f;
          } else if (cp >= 4) {
            const float* src = p.h0 + ((size_t)(b * 64 + cp - 4)) * 800 + ng;
#pragma unroll
            for (int q = 0; q < 4; ++q) {
              float4 f = *(const float4*)(src + q * 4);
              vv[q * 4 + 0] = f.x; vv[q * 4 + 1] = f.y; vv[q * 4 + 2] = f.z; vv[q * 4 + 3] = f.w;
            }
          } else if (cp >= 2) {
#pragma unroll
            for (int i = 0; i < 16; ++i)
              vv[i] = emb[(size_t)(b * 12 + t) * 1600 + (ng + i) * 2 + (cp - 2)];
          } else {
            if (dec) {
              if (t == 0) {
#pragma unroll
                for (int i = 0; i < 16; ++i) vv[i] = 0.f;
              } else {
#pragma unroll
                for (int i = 0; i < 16; ++i)
                  vv[i] = p.dout[((size_t)(b * 12 + t - 1) * 800 + ng + i) * 2 + cp];
              }
            } else {
#pragma unroll
              for (int i = 0; i < 16; ++i)
                vv[i] = p.x_seq[((size_t)(b * 12 + t) * 800 + ng + i) * 2 + cp];
            }
          }
        }
      }
#pragma unroll
      for (int i = 0; i < 16; ++i) {
        union { f16_t h[2]; unsigned u; } pk;
        pk.h[0] = (f16_t)v[0][i];
        pk.h[1] = (f16_t)v[1][i];
        XS32[(n0 + i) * 68 + pass * 32 + rp] = pk.u;
      }
    }
  }
  __syncthreads();

  for (int s = 0; s < 3; ++s) {
    f32x4 acc[4][4];
#pragma unroll
    for (int i = 0; i < 4; ++i)
#pragma unroll
      for (int j = 0; j < 4; ++j) acc[i][j] = (f32x4){0.f, 0.f, 0.f, 0.f};
#pragma unroll
    for (int ks = 0; ks < 4; ++ks) {
      half8 fa[4], fx[4];
#pragma unroll
      for (int mf = 0; mf < 4; ++mf)
        fa[mf] = *(const half8*)(wb + ((size_t)(s * 128 + wm * 64 + mf * 16 + lrow) << 7) + ks * 32 + lgrp * 8);
#pragma unroll
      for (int nt = 0; nt < 4; ++nt)
        fx[nt] = *(const half8*)(XS + (wn * 64 + nt * 16 + lrow) * 136 + ks * 32 + lgrp * 8);
#pragma unroll
      for (int mf = 0; mf < 4; ++mf)
#pragma unroll
        for (int nt = 0; nt < 4; ++nt)
          acc[mf][nt] = __builtin_amdgcn_mfma_f32_16x16x32_f16(fa[mf], fx[nt], acc[mf][nt], 0, 0, 0);
    }
#pragma unroll
    for (int mf = 0; mf < 4; ++mf)
#pragma unroll
      for (int nt = 0; nt < 4; ++nt) {
        int n = nBase + wn * 64 + nt * 16 + lrow;
        if (n >= 800) continue;
#pragma unroll
        for (int j = 0; j < 4; ++j) {
          int c = wm * 64 + mf * 16 + lgrp * 4 + j;
          size_t r = (size_t)(b * 128 + c);
          f16_t val = (f16_t)acc[mf][nt][j];
          if (s == 0) {
            Y0g[r * 800 + n] = val;
          } else {
            int kp = (s - 1) * 800 + n;
            Ybg[((size_t)(kp >> 3) * 8192 + r) * 8 + (kp & 7)] = val;
          }
        }
      }
  }
}

// ================= gate big GEMM body (M=8192) + fused CAND small-proj =================
template <int LAYER>
__device__ void biggate_body(const Params& p, char* smraw, int w0, int dec, int t, float* hcur,
                             const f16_t* __restrict__ Y0g, const f16_t* __restrict__ Ybg,
                             f16_t* __restrict__ Y0c, f16_t* __restrict__ Ybc,
                             f16_t* __restrict__ Uh, int lblk) {
  constexpr int Pin = LAYER ? 64 : 4;
  f16_t* SH = (f16_t*)smraw;
  f16_t* AS = SH;
  f16_t* BS = SH + 6144;
  int tid = threadIdx.x, lane = tid & 63, w = tid >> 6;
  int lrow = lane & 15, lgrp = lane >> 4;
  int wm = w >> 1, wn = w & 1;
  int swz = xcd_swz(lblk, 896);
  int rt = swz / 7;
  int rBase = rt * 64;
  int nTile = swz % 7;
  int b = rt >> 1;
  int rhblk = rt & 1;
  const f16_t* __restrict__ Bbase = p.Bpk + (size_t)nTile * 204800;
  const float* bias = p.bia[w0];

  auto stage = [&](int buf, int ks) {
    gload16(Ybg + ((size_t)(ks * 4 + w) * 8192 + rBase + lane) * 8, AS + buf * 2048 + w * 512);
    gload16(Bbase + (size_t)ks * 4096 + (size_t)(w * 2 + 0) * 512 + lane * 8, BS + buf * 4096 + (w * 2 + 0) * 512);
    gload16(Bbase + (size_t)ks * 4096 + (size_t)(w * 2 + 1) * 512 + lane * 8, BS + buf * 4096 + (w * 2 + 1) * 512);
  };

  f32x4 acc[2][4];
#pragma unroll
  for (int i = 0; i < 2; ++i)
#pragma unroll
    for (int j = 0; j < 4; ++j) acc[i][j] = (f32x4){0.f, 0.f, 0.f, 0.f};

  stage(0, 0);
  stage(1, 1);
  for (int ks = 0; ks < 50; ++ks) {
    if (ks == 49) {
      asm volatile("s_waitcnt vmcnt(0)" ::: "memory");
    } else {
      asm volatile("s_waitcnt vmcnt(3)" ::: "memory");
    }
    __builtin_amdgcn_s_barrier();
    __builtin_amdgcn_sched_barrier(0);
    if (ks + 2 < 50) stage((ks + 2) % 3, ks + 2);
    int cur = ks % 3;
    half8 fa[2], fb[4];
#pragma unroll
    for (int mt = 0; mt < 2; ++mt)
      fa[mt] = *(const half8*)(AS + cur * 2048 + lgrp * 512 + (wm * 32 + mt * 16 + lrow) * 8);
#pragma unroll
    for (int nt = 0; nt < 4; ++nt)
      fb[nt] = *(const half8*)(BS + cur * 4096 + lgrp * 1024 + (wn * 64 + nt * 16 + lrow) * 8);
#pragma unroll
    for (int mt = 0; mt < 2; ++mt)
#pragma unroll
      for (int nt = 0; nt < 4; ++nt)
        acc[mt][nt] = __builtin_amdgcn_mfma_f32_16x16x32_f16(fa[mt], fb[nt], acc[mt][nt], 0, 0, 0);
  }

  if (!rhblk) {
#pragma unroll
    for (int mt = 0; mt < 2; ++mt)
#pragma unroll
      for (int nt = 0; nt < 4; ++nt) {
        int n = nTile * 128 + wn * 64 + nt * 16 + lrow;
        if (n >= 800) continue;
#pragma unroll
        for (int j = 0; j < 4; ++j) {
          int c = wm * 32 + mt * 16 + lgrp * 4 + j;
          int r = rBase + c;
          float v = acc[mt][nt][j] + (float)Y0g[(size_t)r * 800 + n] + bias[c];
          Uh[(size_t)(b * 64 + c) * 800 + n] = (f16_t)sigm(v);
        }
      }
    return;
  }

  f16_t rhv[2][4][4];
#pragma unroll
  for (int mt = 0; mt < 2; ++mt)
#pragma unroll
    for (int nt = 0; nt < 4; ++nt) {
      int n = nTile * 128 + wn * 64 + nt * 16 + lrow;
#pragma unroll
      for (int j = 0; j < 4; ++j) {
        int jj = wm * 32 + mt * 16 + lgrp * 4 + j;
        if (n < 800) {
          int r = rBase + jj;
          float v = acc[mt][nt][j] + (float)Y0g[(size_t)r * 800 + n] + bias[64 + jj];
          float hv = hcur[(size_t)(b * 64 + jj) * 800 + n];
          rhv[mt][nt][j] = (f16_t)(sigm(v) * hv);
        } else {
          rhv[mt][nt][j] = (f16_t)0.f;
        }
      }
    }

  __syncthreads();
  f16_t* Xc = SH;

#pragma unroll
  for (int mt = 0; mt < 2; ++mt)
#pragma unroll
    for (int nt = 0; nt < 4; ++nt) {
      int col = wn * 64 + nt * 16 + lrow;
#pragma unroll
      for (int j = 0; j < 4; ++j) {
        int jj = wm * 32 + mt * 16 + lgrp * 4 + j;
        Xc[col * 136 + Pin + jj] = rhv[mt][nt][j];
      }
    }
  if (LAYER == 1) {
    int ct = tid >> 2, nq = tid & 3;
    const float* src = p.h0 + (size_t)(b * 64 + ct) * 800;
#pragma unroll 8
    for (int i = 0; i < 32; ++i) {
      int nl = nq * 32 + i;
      int n = nTile * 128 + nl;
      float v = (n < 800) ? src[n] : 0.f;
      Xc[nl * 136 + ct] = (f16_t)v;
    }
  } else {
    if (tid < 128) {
      int col = tid;
      int n = nTile * 128 + col;
      float v0 = 0.f, v1 = 0.f, v2 = 0.f, v3 = 0.f;
      if (n < 800) {
        if (dec) {
          if (t > 0) {
            v0 = p.dout[((size_t)(b * 12 + t - 1) * 800 + n) * 2 + 0];
            v1 = p.dout[((size_t)(b * 12 + t - 1) * 800 + n) * 2 + 1];
          }
        } else {
          v0 = p.x_seq[((size_t)(b * 12 + t) * 800 + n) * 2 + 0];
          v1 = p.x_seq[((size_t)(b * 12 + t) * 800 + n) * 2 + 1];
        }
        const float* emb = dec ? p.tye : p.txe;
        v2 = emb[(size_t)(b * 12 + t) * 1600 + n * 2 + 0];
        v3 = emb[(size_t)(b * 12 + t) * 1600 + n * 2 + 1];
      }
      Xc[col * 136 + 0] = (f16_t)v0;
      Xc[col * 136 + 1] = (f16_t)v1;
      Xc[col * 136 + 2] = (f16_t)v2;
      Xc[col * 136 + 3] = (f16_t)v3;
      unsigned* z32 = (unsigned*)(Xc + col * 136 + 68);
#pragma unroll
      for (int q = 0; q < 30; ++q) z32[q] = 0u;
    }
  }
  __syncthreads();

  const f16_t* __restrict__ wc = p.wsp[w0 + 1];
  int cwn = w;
  for (int s = 0; s < 3; ++s) {
    f32x4 ac[4][2];
#pragma unroll
    for (int i = 0; i < 4; ++i)
#pragma unroll
      for (int j = 0; j < 2; ++j) ac[i][j] = (f32x4){0.f, 0.f, 0.f, 0.f};
#pragma unroll
    for (int ks = 0; ks < 4; ++ks) {
      half8 fa[4], fx[2];
#pragma unroll
      for (int mf = 0; mf < 4; ++mf)
        fa[mf] = *(const half8*)(wc + ((size_t)(s * 64 + mf * 16 + lrow) << 7) + ks * 32 + lgrp * 8);
#pragma unroll
      for (int nt = 0; nt < 2; ++nt)
        fx[nt] = *(const half8*)(Xc + (cwn * 32 + nt * 16 + lrow) * 136 + ks * 32 + lgrp * 8);
#pragma unroll
      for (int mf = 0; mf < 4; ++mf)
#pragma unroll
        for (int nt = 0; nt < 2; ++nt)
          ac[mf][nt] = __builtin_amdgcn_mfma_f32_16x16x32_f16(fa[mf], fx[nt], ac[mf][nt], 0, 0, 0);
    }
#pragma unroll
    for (int mf = 0; mf < 4; ++mf)
#pragma unroll
      for (int nt = 0; nt < 2; ++nt) {
        int n = nTile * 128 + cwn * 32 + nt * 16 + lrow;
        if (n >= 800) continue;
#pragma unroll
        for (int j = 0; j < 4; ++j) {
          int c = mf * 16 + lgrp * 4 + j;
          size_t r = (size_t)(b * 64 + c);
          f16_t val = (f16_t)ac[mf][nt][j];
          if (s == 0) {
            Y0c[r * 800 + n] = val;
          } else {
            int kp = (s - 1) * 800 + n;
            Ybc[((size_t)(kp >> 3) * 4096 + r) * 8 + (kp & 7)] = val;
          }
        }
      }
  }
}

// ================= cand big GEMM body (M=4096), GRU h-update epilogue =================
__device__ void bigcand_body(const Params& p, char* smraw, int widx, float* hcur,
                             const f16_t* __restrict__ Y0c, const f16_t* __restrict__ Ybc,
                             const f16_t* __restrict__ Uh, int lblk) {
  f16_t* SH = (f16_t*)smraw;
  f16_t* AS = SH;
  f16_t* BS = SH + 6144;
  int tid = threadIdx.x, lane = tid & 63, w = tid >> 6;
  int lrow = lane & 15, lgrp = lane >> 4;
  int wm = w >> 1, wn = w & 1;
  int swz = xcd_swz(lblk, 448);
  int rBase = (swz / 7) * 64;
  int nTile = swz % 7;
  const f16_t* __restrict__ Bbase = p.Bpk + (size_t)nTile * 204800;
  const float* bias = p.bia[widx];

  auto stage = [&](int buf, int ks) {
    gload16(Ybc + ((size_t)(ks * 4 + w) * 4096 + rBase + lane) * 8, AS + buf * 2048 + w * 512);
    gload16(Bbase + (size_t)ks * 4096 + (size_t)(w * 2 + 0) * 512 + lane * 8, BS + buf * 4096 + (w * 2 + 0) * 512);
    gload16(Bbase + (size_t)ks * 4096 + (size_t)(w * 2 + 1) * 512 + lane * 8, BS + buf * 4096 + (w * 2 + 1) * 512);
  };

  f32x4 acc[2][4];
#pragma unroll
  for (int i = 0; i < 2; ++i)
#pragma unroll
    for (int j = 0; j < 4; ++j) acc[i][j] = (f32x4){0.f, 0.f, 0.f, 0.f};

  stage(0, 0);
  stage(1, 1);
  for (int ks = 0; ks < 50; ++ks) {
    if (ks == 49) {
      asm volatile("s_waitcnt vmcnt(0)" ::: "memory");
    } else {
      asm volatile("s_waitcnt vmcnt(3)" ::: "memory");
    }
    __builtin_amdgcn_s_barrier();
    __builtin_amdgcn_sched_barrier(0);
    if (ks + 2 < 50) stage((ks + 2) % 3, ks + 2);
    int cur = ks % 3;
    half8 fa[2], fb[4];
#pragma unroll
    for (int mt = 0; mt < 2; ++mt)
      fa[mt] = *(const half8*)(AS + cur * 2048 + lgrp * 512 + (wm * 32 + mt * 16 + lrow) * 8);
#pragma unroll
    for (int nt = 0; nt < 4; ++nt)
      fb[nt] = *(const half8*)(BS + cur * 4096 + lgrp * 1024 + (wn * 64 + nt * 16 + lrow) * 8);
#pragma unroll
    for (int mt = 0; mt < 2; ++mt)
#pragma unroll
      for (int nt = 0; nt < 4; ++nt)
        acc[mt][nt] = __builtin_amdgcn_mfma_f32_16x16x32_f16(fa[mt], fb[nt], acc[mt][nt], 0, 0, 0);
  }

#pragma unroll
  for (int mt = 0; mt < 2; ++mt)
#pragma unroll
    for (int nt = 0; nt < 4; ++nt) {
      int n = nTile * 128 + wn * 64 + nt * 16 + lrow;
      if (n >= 800) continue;
#pragma unroll
      for (int j = 0; j < 4; ++j) {
        int r = rBase + wm * 32 + mt * 16 + lgrp * 4 + j;
        int b = r >> 6, c = r & 63;
        float v = acc[mt][nt][j] + (float)Y0c[(size_t)r * 800 + n] + bias[c];
        float u = (float)Uh[(size_t)(b * 64 + c) * 800 + n];
        float hv = hcur[(size_t)(b * 64 + c) * 800 + n];
        hcur[(size_t)(b * 64 + c) * 800 + n] = (1.f - u) * hv + u * tanhf(v);
      }
    }
}

// ================= kernels: single-job and dual-job (encoder pipeline) =================

template <int LAYER>
__global__ void __launch_bounds__(256, 3) s_one(Params p, int widx, int dec, int t) {
  __shared__ __align__(16) char sm[34816];
  small_body<LAYER>(p, sm, widx, dec, t, p.Y0gL[LAYER], p.YbgL[LAYER], blockIdx.x);
}
__global__ void __launch_bounds__(256, 3) s_both(Params p, int t0, int t1) {
  __shared__ __align__(16) char sm[34816];
  if (blockIdx.x < 448)
    small_body<0>(p, sm, 0, 0, t0, p.Y0gL[0], p.YbgL[0], blockIdx.x);
  else
    small_body<1>(p, sm, 2, 0, t1, p.Y0gL[1], p.YbgL[1], blockIdx.x - 448);
}

template <int LAYER>
__global__ void __launch_bounds__(256, 4) gg_one(Params p, int w0, int dec, int t) {
  __shared__ __align__(16) char sm[36864];
  biggate_body<LAYER>(p, sm, w0, dec, t, LAYER ? p.h1 : p.h0, p.Y0gL[LAYER], p.YbgL[LAYER],
                      p.Y0cL[LAYER], p.YbcL[LAYER], p.UhL[LAYER], blockIdx.x);
}
__global__ void __launch_bounds__(256, 4) gg_both(Params p, int t0, int t1) {
  __shared__ __align__(16) char sm[36864];
  if (blockIdx.x < 896)
    biggate_body<0>(p, sm, 0, 0, t0, p.h0, p.Y0gL[0], p.YbgL[0], p.Y0cL[0], p.YbcL[0], p.UhL[0], blockIdx.x);
  else
    biggate_body<1>(p, sm, 2, 0, t1, p.h1, p.Y0gL[1], p.YbgL[1], p.Y0cL[1], p.YbcL[1], p.UhL[1], blockIdx.x - 896);
}

__global__ void __launch_bounds__(256, 4) gc_one(Params p, int widx, int layer) {
  __shared__ __align__(16) char sm[36864];
  bigcand_body(p, sm, widx, layer ? p.h1 : p.h0, p.Y0cL[layer], p.YbcL[layer], p.UhL[layer], blockIdx.x);
}
__global__ void __launch_bounds__(256, 4) gc_both(Params p) {
  __shared__ __align__(16) char sm[36864];
  if (blockIdx.x < 448)
    bigcand_body(p, sm, 1, p.h0, p.Y0cL[0], p.YbcL[0], p.UhL[0], blockIdx.x);
  else
    bigcand_body(p, sm, 3, p.h1, p.Y0cL[1], p.YbcL[1], p.UhL[1], blockIdx.x - 448);
}

// ================= attention =================

__global__ void __launch_bounds__(256) k_att1(Params p) {
  int gwid = (blockIdx.x * blockDim.x + threadIdx.x) >> 6;
  int nw = (gridDim.x * blockDim.x) >> 6;
  int lane = threadIdx.x & 63;
  for (int tile = gwid; tile < 1024; tile += nw) {
    int cx = tile & 15, b = tile >> 4;
    float acc[8] = {};
    const float* hrow = p.h1 + (size_t)b * 51200 + cx * 3200;
    const float* wbase = p.Wat + (size_t)cx * 3200 * 8;
    for (int i = lane; i < 3200; i += 64) {
      float hv = hrow[i];
      const float* wr = wbase + (size_t)i * 8;
#pragma unroll
      for (int j = 0; j < 8; ++j) acc[j] += hv * wr[j];
    }
#pragma unroll
    for (int s = 1; s < 64; s <<= 1) {
#pragma unroll
      for (int j = 0; j < 8; ++j) acc[j] += __shfl_xor(acc[j], s);
    }
    if (lane == 0) {
#pragma unroll
      for (int j = 0; j < 8; ++j) p.partial[((size_t)b * 16 + cx) * 8 + j] = acc[j];
    }
  }
}

__global__ void __launch_bounds__(256) k_att2(Params p, int t) {
  int b = blockIdx.x >> 2, q4 = blockIdx.x & 3;
  int tid = threadIdx.x;
  float qv[8] = {};
  for (int cx = 0; cx < 16; ++cx)
#pragma unroll
    for (int j = 0; j < 8; ++j) qv[j] += p.partial[((size_t)b * 16 + cx) * 8 + j];
  float sco[4], mx = -1e30f;
#pragma unroll
  for (int m = 0; m < 4; ++m) {
    float s = 0.f;
#pragma unroll
    for (int d = 0; d < 8; ++d) s += qv[d] * p.mem[m * 8 + d];
    sco[m] = s;
    mx = fmaxf(mx, s);
  }
  float se = 0.f;
#pragma unroll
  for (int m = 0; m < 4; ++m) { sco[m] = expf(sco[m] - mx); se += sco[m]; }
  float attv[8];
#pragma unroll
  for (int d = 0; d < 8; ++d) {
    float av = 0.f;
#pragma unroll
    for (int m = 0; m < 4; ++m) av += (sco[m] / se) * p.mem[m * 8 + d];
    attv[d] = av;
  }
  if (tid >= 200) return;
  int n = q4 * 200 + tid;
  float attm[8];
#pragma unroll
  for (int d = 0; d < 8; ++d) {
    float s = 0.f;
#pragma unroll
    for (int m = 0; m < 8; ++m) s += attv[m] * p.fc[(size_t)m * 6400 + n * 8 + d];
    attm[d] = s;
  }
  float o0 = p.projb[0], o1 = p.projb[1];
  const float* hb = p.h1 + (size_t)b * 51200 + n;
#pragma unroll 16
  for (int j = 0; j < 64; ++j) {
    float hv = hb[(size_t)j * 800];
    o0 += hv * p.projW[j * 2 + 0];
    o1 += hv * p.projW[j * 2 + 1];
  }
#pragma unroll
  for (int d = 0; d < 8; ++d) {
    o0 += attm[d] * p.projW[(64 + d) * 2 + 0];
    o1 += attm[d] * p.projW[(64 + d) * 2 + 1];
  }
  size_t base = ((size_t)(b * 12 + t) * 800 + n) * 2;
  p.dout[base + 0] = fmaxf(o0, 0.f);
  p.dout[base + 1] = fmaxf(o1, 0.f);
}

// ================= host =================

extern "C" void kernel_launch(void* const* d_in, const int* in_sizes, int n_in,
                              void* d_out, int out_size, void* d_ws, size_t ws_size,
                              hipStream_t stream) {
  Params P;
  P.x_seq = (const float*)d_in[0];
  P.t_x = (const float*)d_in[1];
  P.t_y = (const float*)d_in[2];
  P.G = (const float*)d_in[3];
  P.Wraw[0] = (const float*)d_in[4];  P.bia[0] = (const float*)d_in[5];
  P.Wraw[1] = (const float*)d_in[6];  P.bia[1] = (const float*)d_in[7];
  P.Wraw[2] = (const float*)d_in[8];  P.bia[2] = (const float*)d_in[9];
  P.Wraw[3] = (const float*)d_in[10]; P.bia[3] = (const float*)d_in[11];
  P.Wraw[4] = (const float*)d_in[12]; P.bia[4] = (const float*)d_in[13];
  P.Wraw[5] = (const float*)d_in[14]; P.bia[5] = (const float*)d_in[15];
  P.Wraw[6] = (const float*)d_in[16]; P.bia[6] = (const float*)d_in[17];
  P.Wraw[7] = (const float*)d_in[18]; P.bia[7] = (const float*)d_in[19];
  P.mW1 = (const float*)d_in[20];
  P.mb1 = (const float*)d_in[21];
  P.mW2 = (const float*)d_in[22];
  P.mb2 = (const float*)d_in[23];
  P.mem = (const float*)d_in[24];
  P.Wa = (const float*)d_in[25];
  P.fc = (const float*)d_in[26];
  P.projW = (const float*)d_in[27];
  P.projb = (const float*)d_in[28];
  P.dout = (float*)d_out;

  float* ws = (float*)d_ws;
  size_t off = 0;
  auto alloc = [&](size_t nel) { float* q = ws + off; off += (nel + 3) & ~(size_t)3; return q; };
  P.T2h = (f16_t*)alloc(320000);
  P.Bpk = (f16_t*)alloc((size_t)7 * 50 * 4096 / 2);
  for (int l = 0; l < 2; ++l) {
    P.Y0gL[l] = (f16_t*)alloc((size_t)8192 * 800 / 2);
    P.YbgL[l] = (f16_t*)alloc((size_t)1600 * 8192 / 2);
    P.Y0cL[l] = (f16_t*)alloc((size_t)4096 * 800 / 2);
    P.YbcL[l] = (f16_t*)alloc((size_t)1600 * 4096 / 2);
    P.UhL[l] = (f16_t*)alloc((size_t)4096 * 800 / 2);
  }
  P.h0 = alloc((size_t)4096 * 800);
  P.h1 = alloc((size_t)4096 * 800);
  P.txe = alloc((size_t)768 * 1600);
  P.tye = alloc((size_t)768 * 1600);
  P.hidb = alloc(15360);
  P.partial = alloc(8192);
  P.Wat = alloc(409600);
  for (int w = 0; w < 8; ++w) {
    int cand = w & 1;
    int NC = cand ? 64 : 128;
    P.wsp[w] = (f16_t*)alloc((size_t)3 * NC * 128 / 2);
  }

  k_pre0<<<512, 256, 0, stream>>>(P);
  k_pre1<<<512, 256, 0, stream>>>(P);
  k_pre2<<<512, 256, 0, stream>>>(P);

  // ---- encoder: software-pipelined across layers ----
  // stage 0: L0(t=0) only
  s_one<0><<<448, 256, 0, stream>>>(P, 0, 0, 0);
  gg_one<0><<<896, 256, 0, stream>>>(P, 0, 0, 0);
  gc_one<<<448, 256, 0, stream>>>(P, 1, 0);
  // stages 1..11: L0(s) || L1(s-1)
  for (int s = 1; s <= 11; ++s) {
    s_both<<<896, 256, 0, stream>>>(P, s, s - 1);
    gg_both<<<1792, 256, 0, stream>>>(P, s, s - 1);
    gc_both<<<896, 256, 0, stream>>>(P);
  }
  // stage 12: L1(t=11) only
  s_one<1><<<448, 256, 0, stream>>>(P, 2, 0, 11);
  gg_one<1><<<896, 256, 0, stream>>>(P, 2, 0, 11);
  gc_one<<<448, 256, 0, stream>>>(P, 3, 1);

  // ---- decoder: serial (dout feedback) ----
  for (int t = 0; t < 12; ++t) {
    s_one<0><<<448, 256, 0, stream>>>(P, 4, 1, t);
    gg_one<0><<<896, 256, 0, stream>>>(P, 4, 1, t);
    gc_one<<<448, 256, 0, stream>>>(P, 5, 0);
    s_one<1><<<448, 256, 0, stream>>>(P, 6, 1, t);
    gg_one<1><<<896, 256, 0, stream>>>(P, 6, 1, t);
    gc_one<<<448, 256, 0, stream>>>(P, 7, 1);
    k_att1<<<256, 256, 0, stream>>>(P);
    k_att2<<<256, 256, 0, stream>>>(P, t);
  }
}